// Round 1
// baseline (398.688 us; speedup 1.0000x reference)
//
#include <hip/hip_runtime.h>
#include <hip/hip_bf16.h>

// Problem constants (B=4, S=2048, D_MODEL=1024, H=16, DH=64, RANK=256, NPRIM=16, top_k=4)
#define TOK 8192
#define SEQ 2048
#define CT  32          // scan chunk length
#define NC  64          // chunks per sequence

typedef __attribute__((ext_vector_type(8))) short bf16x8;   // 8 bf16 = 4 VGPRs
typedef __attribute__((ext_vector_type(4))) float f32x4;
typedef unsigned short u16;
typedef unsigned int   u32;

__device__ __forceinline__ u16 f2bf(float f) {
    u32 u = __float_as_uint(f);
    u = (u + 0x7FFFu + ((u >> 16) & 1u)) >> 16;   // RNE
    return (u16)u;
}
__device__ __forceinline__ float b2f(u16 h) { return __uint_as_float(((u32)h) << 16); }
__device__ __forceinline__ float sigf(float z) { return 1.f / (1.f + __expf(-z)); }

// Top-4 of 16 logits + softmax over the kept 4 (== softmax->topk->renorm, exact).
__device__ __forceinline__ void topk4(const float* __restrict__ lg, int* idx, float* wv)
{
    float v[16];
    #pragma unroll
    for (int i = 0; i < 16; i++) v[i] = lg[i];
    bool used[16];
    #pragma unroll
    for (int i = 0; i < 16; i++) used[i] = false;
    float val[4];
    #pragma unroll
    for (int k = 0; k < 4; k++) {
        int bi = 0; float bv = -3.0e38f;
        #pragma unroll
        for (int i = 0; i < 16; i++)
            if (!used[i] && v[i] > bv) { bv = v[i]; bi = i; }
        used[bi] = true; idx[k] = bi; val[k] = bv;
    }
    float e[4], s = 0.f;
    #pragma unroll
    for (int k = 0; k < 4; k++) { e[k] = expf(val[k] - val[0]); s += e[k]; }
    #pragma unroll
    for (int k = 0; k < 4; k++) wv[k] = e[k] / s;
}

// ---------------------------------------------------------------------------
// prep: one dispatch, branch by block range.
//   [0, 2048)    : x cast -> bf16 AND decay dec[t][h] (x row held in regs)
//   [2048, 3072) : out_gate_w cast
//   [3072, 4096) : out_proj_w cast
//   [4096, 6144) : gather selected prims -> gU (w folded), gVT (transposed)
// ---------------------------------------------------------------------------
__global__ __launch_bounds__(256)
void prep(const float* __restrict__ x, const float* __restrict__ ogw,
          const float* __restrict__ opw,
          const float* __restrict__ qU, const float* __restrict__ kU,
          const float* __restrict__ vU,
          const float* __restrict__ qV, const float* __restrict__ kV,
          const float* __restrict__ vV,
          const float* __restrict__ ql, const float* __restrict__ kl,
          const float* __restrict__ vl, const float* __restrict__ gl,
          const float* __restrict__ dw, const float* __restrict__ db,
          u16* __restrict__ xb, u16* __restrict__ ogwb, u16* __restrict__ opwb,
          u16* __restrict__ gU, u16* __restrict__ gVT, float* __restrict__ dec)
{
    const int blk = blockIdx.x;
    const int tid = threadIdx.x;

    if (blk < 2048) {
        // ---- x cast + decay: one wave per token ----
        const int wave = tid >> 6, lane = tid & 63;
        const int t = blk * 4 + wave;
        const float4* x4 = (const float4*)(x + (size_t)t * 1024);
        float4 xv[4];
        #pragma unroll
        for (int i = 0; i < 4; i++) xv[i] = x4[lane + 64 * i];
        // cast-store the row
        uint2* xrow = (uint2*)(xb + (size_t)t * 1024);
        #pragma unroll
        for (int i = 0; i < 4; i++) {
            __align__(8) u16 tq[4] = { f2bf(xv[i].x), f2bf(xv[i].y),
                                       f2bf(xv[i].z), f2bf(xv[i].w) };
            xrow[lane + 64 * i] = *(const uint2*)tq;
        }
        // 16 head dots from the same registers
        float p[16];
        #pragma unroll
        for (int h = 0; h < 16; h++) {
            const float4* w4 = (const float4*)(dw + (size_t)h * 1024);
            float s = 0.f;
            #pragma unroll
            for (int i = 0; i < 4; i++) {
                const float4 wv = w4[lane + 64 * i];
                s = fmaf(xv[i].x, wv.x, fmaf(xv[i].y, wv.y,
                    fmaf(xv[i].z, wv.z, fmaf(xv[i].w, wv.w, s))));
            }
            p[h] = s;
        }
        #pragma unroll
        for (int off = 32; off > 0; off >>= 1)
            #pragma unroll
            for (int h = 0; h < 16; h++) p[h] += __shfl_xor(p[h], off);
        if (lane == 0) {
            #pragma unroll
            for (int h = 0; h < 16; h++)
                dec[(size_t)t * 16 + h] = 1.f / (1.f + __expf(p[h] + db[h]));
        }
        return;
    }
    if (blk < 4096) {
        // ---- weight casts: 1 float4 per thread ----
        const float* src; u16* dst;
        int off;
        if (blk < 3072) { src = ogw; dst = ogwb; off = (blk - 2048) * 256 + tid; }
        else            { src = opw; dst = opwb; off = (blk - 3072) * 256 + tid; }
        const float4 v = ((const float4*)src)[off];
        __align__(8) u16 t[4] = { f2bf(v.x), f2bf(v.y), f2bf(v.z), f2bf(v.w) };
        ((uint2*)dst)[off] = *(const uint2*)t;
        return;
    }
    // ---- gather (topk inline, exact) ----
    {
        const int local = blk - 4096;
        const int z = local >> 8;              // 0..7
        const int bx = local & 15, by = (local >> 4) & 15;
        const int p = z & 3;
        const float* lg = (p == 0) ? ql : (p == 1) ? kl : (p == 2) ? vl : gl;
        int idx[4]; float wsel[4];
        topk4(lg, idx, wsel);

        if (z < 4) {
            // V^T gather: gVT[p][o][k=s*256+r] = V_sel[s][r][o]
            const float* V = (p == 0) ? qV : (p == 1) ? kV : vV;
            const int o0 = bx * 64, k0 = by * 64;
            const int s = k0 >> 8, r0 = k0 & 255;
            const float* Vb = V + (size_t)idx[s] * (256 * 1024);
            __shared__ float tile[64][68];
            const int rr = tid >> 4, cc = (tid & 15) << 2;
            #pragma unroll
            for (int i = 0; i < 4; i++) {
                const float4 v = *(const float4*)(Vb + (size_t)(r0 + rr + 16 * i) * 1024 + o0 + cc);
                *(float4*)&tile[rr + 16 * i][cc] = v;
            }
            __syncthreads();
            const int oo = tid >> 4, kk = (tid & 15) << 2;
            u16* out = gVT + (size_t)p * 1048576;
            #pragma unroll
            for (int i = 0; i < 4; i++) {
                __align__(8) u16 t[4];
                #pragma unroll
                for (int j = 0; j < 4; j++) t[j] = f2bf(tile[kk + j][oo + 16 * i]);
                *(uint2*)(out + (size_t)(o0 + oo + 16 * i) * 1024 + k0 + kk) = *(const uint2*)t;
            }
        } else {
            // U gather: gU[p][d][k=s*256+r] = w_s * U_sel[s][d][r]
            const float* U = (p == 0) ? qU : (p == 1) ? kU : vU;
            const int d0 = bx * 64, k0 = by * 64;
            const int s = k0 >> 8, r0 = k0 & 255;
            const float* Ub = U + (size_t)idx[s] * (1024 * 256);
            const float wq = wsel[s];
            u16* out = gU + (size_t)p * 1048576;
            const int rr = tid >> 4, cc = (tid & 15) << 2;
            #pragma unroll
            for (int i = 0; i < 4; i++) {
                const float4 v = *(const float4*)(Ub + (size_t)(d0 + rr + 16 * i) * 256 + r0 + cc);
                __align__(8) u16 t[4] = { f2bf(v.x * wq), f2bf(v.y * wq),
                                          f2bf(v.z * wq), f2bf(v.w * wq) };
                *(uint2*)(out + (size_t)(d0 + rr + 16 * i) * 1024 + k0 + cc) = *(const uint2*)t;
            }
        }
    }
}

// ---------------------------------------------------------------------------
// 64x64-tile bf16 MFMA GEMM for W_eff^T: C[m][n] = sum_k A[m,k]*B[n,k],
// M=N=K=1024, z batches slices of 1M elements. grid (16,16,4) -> 4 blocks/CU.
// ---------------------------------------------------------------------------
__global__ __launch_bounds__(256)
void mfma_gemm64(const u16* __restrict__ Asrc, const u16* __restrict__ Bsrc,
                 u16* __restrict__ Cout)
{
    __shared__ u16 As[64 * 64];
    __shared__ u16 Bs[64 * 64];
    const int z = blockIdx.z;
    const u16* A = Asrc + (size_t)z * 1048576;
    const u16* B = Bsrc + (size_t)z * 1048576;
    u16* C = Cout + (size_t)z * 1048576;
    const int tid = threadIdx.x, lane = tid & 63, wave = tid >> 6;
    const int m0 = blockIdx.y * 64, n0 = blockIdx.x * 64;
    const int wn = wave * 16;

    f32x4 acc[4];
    #pragma unroll
    for (int i = 0; i < 4; i++) acc[i] = (f32x4)0.f;

    for (int k0 = 0; k0 < 1024; k0 += 64) {
        __syncthreads();
        #pragma unroll
        for (int it = 0; it < 2; it++) {
            const int c   = it * 256 + tid;
            const int row = c >> 3, j = c & 7;
            const int g   = j ^ (row & 7);
            const u16* ga = A + (size_t)(m0 + row) * 1024 + k0 + g * 8;
            __builtin_amdgcn_global_load_lds(
                (const __attribute__((address_space(1))) u32*)ga,
                (__attribute__((address_space(3))) u32*)&As[(it * 256 + wave * 64) * 8],
                16, 0, 0);
            const u16* gb = B + (size_t)(n0 + row) * 1024 + k0 + g * 8;
            __builtin_amdgcn_global_load_lds(
                (const __attribute__((address_space(1))) u32*)gb,
                (__attribute__((address_space(3))) u32*)&Bs[(it * 256 + wave * 64) * 8],
                16, 0, 0);
        }
        __syncthreads();
        #pragma unroll
        for (int ks = 0; ks < 2; ks++) {
            const int gk = ks * 4 + (lane >> 4);
            const int rn = wn + (lane & 15);
            const int jb = gk ^ (rn & 7);
            const bf16x8 bfr = *(const bf16x8*)&Bs[rn * 64 + jb * 8];
            #pragma unroll
            for (int mi = 0; mi < 4; mi++) {
                const int rm = mi * 16 + (lane & 15);
                const int ja = gk ^ (rm & 7);
                const bf16x8 af = *(const bf16x8*)&As[rm * 64 + ja * 8];
                acc[mi] = __builtin_amdgcn_mfma_f32_16x16x32_bf16(af, bfr, acc[mi], 0, 0, 0);
            }
        }
    }
    const int col_l = lane & 15, row_l = (lane >> 4) * 4;
    #pragma unroll
    for (int mi = 0; mi < 4; mi++)
        #pragma unroll
        for (int i = 0; i < 4; i++)
            C[(size_t)(m0 + mi * 16 + row_l + i) * 1024 + n0 + wn + col_l] = f2bf(acc[mi][i]);
}

// ---------------------------------------------------------------------------
// 256x256-tile 8-phase bf16 MFMA GEMM (T2+T3+T4+T5 stack, m201-style schedule
// reconstructed in plain HIP). M=8192, N=1024, K=1024, z in {0..4} from the
// block decode. A (xb) is shared across z; B/C are z-strided.
//
// Geometry: 512 threads = 8 waves (2M x 4N); per-wave C = 128x64 = acc[8][4].
// LDS: [2 buf][A,B][2 half][128x64 bf16] = 128 KiB -> 1 block/CU, 2 waves/SIMD.
// Halves are quadrant-aligned (A-half0 = qm=0 rows of BOTH wave groups, B-half0
// = qn=0 cols of all 4 wave groups), so each LDS region's last read phase is
// unique:  A-h0: ph1   B-h0: ph1   B-h1: ph2   A-h1: ph3   (regs reused after).
// Stage issue schedule (all after the freeing phase's end barrier):
//   ph1: A-h1(t+1), B-h1(t+1)   ph2: A-h0(t+2)   ph4: B-h0(t+2)
// Counted waits: vmcnt(8) at ph1-end and ph4-end (12 loads in flight, drain
// only the 2 oldest half-tiles, each issued >=4 phases earlier). Never 0 in
// the main loop; tail peels to vmcnt(4)/vmcnt(0).
// REQUIRES grid == (640,1,1), 512 threads. 640%8==0 -> XCD decode bijective.
// ---------------------------------------------------------------------------
__global__ __launch_bounds__(512)
void mfma_gemm256(const u16* __restrict__ Asrc, const u16* __restrict__ Bt,
                  u16* __restrict__ Cout)
{
    __shared__ __align__(16) u16 Alds[2][2][8192];   // [buf][half(qm)][128*64]
    __shared__ __align__(16) u16 Blds[2][2][8192];   // [buf][half(qn)][128*64]

    const int flat  = blockIdx.x;
    const int xcd   = flat & 7;          // round-robin dispatch -> XCD id
    const int local = flat >> 3;         // 0..79, contiguous per XCD
    const int zb    = local >> 4;        // 0..4   (per-XCD: 16 blocks per z)
    const int rem   = local & 15;
    const int m0    = (xcd * 4 + (rem >> 2)) * 256;  // per-XCD A stripe: 2 MB
    const int n0    = (rem & 3) * 256;               // B slice: 2 MB -> 4MB = L2

    const u16* A = Asrc;                               // shared across z
    const u16* B = Bt + (size_t)zb * 1048576;
    u16*       C = Cout + (size_t)zb * 8388608;

    const int tid  = threadIdx.x;
    const int lane = tid & 63, wave = tid >> 6;
    const int wmi  = wave >> 2, wni = wave & 3;        // 2 x 4 wave grid
    const int l15  = lane & 15, l4 = lane >> 4;

    f32x4 acc[8][4];
    #pragma unroll
    for (int i = 0; i < 8; i++)
        #pragma unroll
        for (int j = 0; j < 4; j++) acc[i][j] = (f32x4)0.f;

    bf16x8 a_fr[2][4];        // [ks][m-tile within quadrant]
    bf16x8 b_fr[2][2][2];     // [qn][ks][n-tile within quadrant]

// --- staging: linear LDS dest (wave-uniform base), swizzle on GLOBAL source.
#define STAGE_A(BUFP, HALF, T) do {                                           \
    _Pragma("unroll")                                                         \
    for (int it_ = 0; it_ < 2; it_++) {                                       \
        const int bc_ = it_ * 512 + wave * 64;                                \
        const int c_  = bc_ + lane;                                           \
        const int r_  = c_ >> 3, j_ = c_ & 7;                                 \
        const int g_  = j_ ^ (r_ & 7);                                        \
        const int gr_ = m0 + ((r_ >> 6) << 7) + (HALF) * 64 + (r_ & 63);      \
        const u16* ga_ = A + (size_t)gr_ * 1024 + (T) * 64 + g_ * 8;          \
        __builtin_amdgcn_global_load_lds(                                     \
            (const __attribute__((address_space(1))) u32*)ga_,                \
            (__attribute__((address_space(3))) u32*)&(BUFP)[(HALF)][bc_ * 8], \
            16, 0, 0);                                                        \
    } } while (0)

#define STAGE_B(BUFP, HALF, T) do {                                           \
    _Pragma("unroll")                                                         \
    for (int it_ = 0; it_ < 2; it_++) {                                       \
        const int bc_ = it_ * 512 + wave * 64;                                \
        const int c_  = bc_ + lane;                                           \
        const int r_  = c_ >> 3, j_ = c_ & 7;                                 \
        const int g_  = j_ ^ (r_ & 7);                                        \
        const int gr_ = n0 + ((r_ >> 5) << 6) + (HALF) * 32 + (r_ & 31);      \
        const u16* gb_ = B + (size_t)gr_ * 1024 + (T) * 64 + g_ * 8;          \
        __builtin_amdgcn_global_load_lds(                                     \
            (const __attribute__((address_space(1))) u32*)gb_,                \
            (__attribute__((address_space(3))) u32*)&(BUFP)[(HALF)][bc_ * 8], \
            16, 0, 0);                                                        \
    } } while (0)

#define READ_A(BUFP, QM) do {                                                 \
    _Pragma("unroll") for (int ks_ = 0; ks_ < 2; ks_++)                       \
    _Pragma("unroll") for (int m4_ = 0; m4_ < 4; m4_++) {                     \
        const int r_  = wmi * 64 + m4_ * 16 + l15;                            \
        const int gk_ = ks_ * 4 + l4;                                         \
        a_fr[ks_][m4_] =                                                      \
            *(const bf16x8*)&(BUFP)[QM][r_ * 64 + ((gk_ ^ (r_ & 7)) * 8)];    \
    } } while (0)

#define READ_B(BUFP, QN) do {                                                 \
    _Pragma("unroll") for (int ks_ = 0; ks_ < 2; ks_++)                       \
    _Pragma("unroll") for (int n2_ = 0; n2_ < 2; n2_++) {                     \
        const int r_  = wni * 32 + n2_ * 16 + l15;                            \
        const int gk_ = ks_ * 4 + l4;                                         \
        b_fr[QN][ks_][n2_] =                                                  \
            *(const bf16x8*)&(BUFP)[QN][r_ * 64 + ((gk_ ^ (r_ & 7)) * 8)];    \
    } } while (0)

#define MFMA_PH(QM, QN) do {                                                  \
    __builtin_amdgcn_s_setprio(1);                                            \
    _Pragma("unroll") for (int ks_ = 0; ks_ < 2; ks_++)                       \
    _Pragma("unroll") for (int m4_ = 0; m4_ < 4; m4_++)                       \
    _Pragma("unroll") for (int n2_ = 0; n2_ < 2; n2_++)                       \
        acc[(QM) * 4 + m4_][(QN) * 2 + n2_] =                                 \
            __builtin_amdgcn_mfma_f32_16x16x32_bf16(                          \
                a_fr[ks_][m4_], b_fr[QN][ks_][n2_],                           \
                acc[(QM) * 4 + m4_][(QN) * 2 + n2_], 0, 0, 0);                \
    __builtin_amdgcn_s_setprio(0);                                            \
} while (0)

#define BAR()    __asm__ volatile("s_barrier" ::: "memory")
#define VMCNT8() __asm__ volatile("s_waitcnt vmcnt(8)" ::: "memory")
#define VMCNT4() __asm__ volatile("s_waitcnt vmcnt(4)" ::: "memory")
#define VMCNT0() __asm__ volatile("s_waitcnt vmcnt(0)" ::: "memory")

    // prologue: issue order fixes the per-wave vmcnt ledger:
    //   [A0h0 B0h0 A0h1 B0h1 A1h0 B1h0] = 12 loads; vmcnt(8) completes A0h0,B0h0.
    STAGE_A(Alds[0], 0, 0);
    STAGE_B(Blds[0], 0, 0);
    STAGE_A(Alds[0], 1, 0);
    STAGE_B(Blds[0], 1, 0);
    STAGE_A(Alds[1], 0, 1);
    STAGE_B(Blds[1], 0, 1);
    VMCNT8(); BAR();

    #pragma unroll 1
    for (int t = 0; t < 16; ++t) {
        const int b = t & 1, nb = b ^ 1;
        u16 (*Ab)[8192] = Alds[b];
        u16 (*Bb)[8192] = Blds[b];

        // ---- phase 1: quadrant (0,0) ----
        READ_A(Ab, 0);
        READ_B(Bb, 0);
        if (t + 1 < 16) { STAGE_A(Alds[nb], 1, t + 1); STAGE_B(Blds[nb], 1, t + 1); }
        BAR();
        MFMA_PH(0, 0);
        if (t < 15) { VMCNT8(); } else { VMCNT0(); }   // completes A-h1(t),B-h1(t)
        BAR();

        // ---- phase 2: quadrant (0,1) ----  (a_fr reused)
        READ_B(Bb, 1);
        if (t + 2 < 16) STAGE_A(Alds[b], 0, t + 2);    // A-h0(b) freed at ph1-end
        BAR();
        MFMA_PH(0, 1);
        BAR();

        // ---- phase 3: quadrant (1,0) ----  (b_fr[0] reused)
        READ_A(Ab, 1);
        BAR();
        MFMA_PH(1, 0);
        BAR();

        // ---- phase 4: quadrant (1,1) ----  (a_fr + b_fr[1] reused)
        if (t + 2 < 16) STAGE_B(Blds[b], 0, t + 2);    // B-h0(b) freed at ph1-end
        BAR();
        MFMA_PH(1, 1);
        if (t + 2 < 16)      { VMCNT8(); }             // completes A-h0(t+1),B-h0(t+1)
        else if (t + 1 < 16) { VMCNT4(); }             // t==14 tail
        BAR();
    }

#undef STAGE_A
#undef STAGE_B
#undef READ_A
#undef READ_B
#undef MFMA_PH
#undef BAR
#undef VMCNT8
#undef VMCNT4
#undef VMCNT0

    // epilogue: C/D layout col=lane&15, row=(lane>>4)*4+reg  [m89-verified]
    const int col_l = lane & 15, row_l = (lane >> 4) * 4;
    #pragma unroll
    for (int mi = 0; mi < 8; mi++)
        #pragma unroll
        for (int ni = 0; ni < 4; ni++)
            #pragma unroll
            for (int i = 0; i < 4; i++) {
                const int rw = m0 + wmi * 128 + mi * 16 + row_l + i;
                const int cn = n0 + wni * 64 + ni * 16 + col_l;
                C[(size_t)rw * 1024 + cn] = f2bf(acc[mi][ni][i]);
            }
}

// ---------------------------------------------------------------------------
// 128x128-tile bf16 MFMA GEMM, M=8192, N=K=1024, z-batched. XCD-swizzled
// block decode (flat%8 = XCD under round-robin) pins an 8-row m-group per
// XCD: per-z working set A 2MB + B 2MB fits the 4MB XCD L2.
// REQUIRES grid == (8, 64, Z).  (Kept for the final fp32-out projection.)
// ---------------------------------------------------------------------------
template<int OUTBF>
__global__ __launch_bounds__(256)
void mfma_gemm(const u16* __restrict__ Asrc, const u16* __restrict__ Bt,
               void* __restrict__ Cout, size_t astride, size_t bstride, size_t cstride)
{
    __shared__ u16 As[128 * 64];
    __shared__ u16 Bs[128 * 64];
    const int flat = blockIdx.x + 8 * (blockIdx.y + 64 * blockIdx.z);
    const int xcd = flat & 7;
    const int r   = flat >> 3;
    const int nb = r & 7, mlocal = (r >> 3) & 7, zb = r >> 6;
    const int m0 = (xcd * 8 + mlocal) * 128, n0 = nb * 128;

    const u16* A = Asrc + (size_t)zb * astride;
    const u16* B = Bt   + (size_t)zb * bstride;
    const int tid  = threadIdx.x;
    const int lane = tid & 63, wave = tid >> 6;
    const int wm = (wave >> 1) * 64, wn = (wave & 1) * 64;

    f32x4 acc[4][4];
    #pragma unroll
    for (int i = 0; i < 4; i++)
        #pragma unroll
        for (int j = 0; j < 4; j++) acc[i][j] = (f32x4)0.f;

    for (int k0 = 0; k0 < 1024; k0 += 64) {
        __syncthreads();
        #pragma unroll
        for (int it = 0; it < 4; it++) {
            const int c   = it * 256 + tid;
            const int row = c >> 3, j = c & 7;
            const int g   = j ^ (row & 7);
            const u16* ga = A + (size_t)(m0 + row) * 1024 + k0 + g * 8;
            __builtin_amdgcn_global_load_lds(
                (const __attribute__((address_space(1))) u32*)ga,
                (__attribute__((address_space(3))) u32*)&As[(it * 256 + wave * 64) * 8],
                16, 0, 0);
            const u16* gb = B + (size_t)(n0 + row) * 1024 + k0 + g * 8;
            __builtin_amdgcn_global_load_lds(
                (const __attribute__((address_space(1))) u32*)gb,
                (__attribute__((address_space(3))) u32*)&Bs[(it * 256 + wave * 64) * 8],
                16, 0, 0);
        }
        __syncthreads();
        #pragma unroll
        for (int ks = 0; ks < 2; ks++) {
            bf16x8 af[4], bfr[4];
            const int gk = ks * 4 + (lane >> 4);
            #pragma unroll
            for (int mi = 0; mi < 4; mi++) {
                const int rr  = wm + mi * 16 + (lane & 15);
                const int ja = gk ^ (rr & 7);
                af[mi] = *(const bf16x8*)&As[rr * 64 + ja * 8];
                const int rn = wn + mi * 16 + (lane & 15);
                const int jb = gk ^ (rn & 7);
                bfr[mi] = *(const bf16x8*)&Bs[rn * 64 + jb * 8];
            }
            #pragma unroll
            for (int mi = 0; mi < 4; mi++)
                #pragma unroll
                for (int ni = 0; ni < 4; ni++)
                    acc[mi][ni] = __builtin_amdgcn_mfma_f32_16x16x32_bf16(
                        af[mi], bfr[ni], acc[mi][ni], 0, 0, 0);
        }
    }
    // epilogue: C/D layout col=lane&15, row=(lane>>4)*4+reg  [m89-verified]
    const int col_l = lane & 15, row_l = (lane >> 4) * 4;
    if (OUTBF) {
        u16* C = (u16*)Cout + (size_t)zb * cstride;
        #pragma unroll
        for (int mi = 0; mi < 4; mi++)
            #pragma unroll
            for (int ni = 0; ni < 4; ni++)
                #pragma unroll
                for (int i = 0; i < 4; i++) {
                    const int rw  = m0 + wm + mi * 16 + row_l + i;
                    const int cn = n0 + wn + ni * 16 + col_l;
                    C[(size_t)rw * 1024 + cn] = f2bf(acc[mi][ni][i]);
                }
    } else {
        float* C = (float*)Cout + (size_t)zb * cstride;
        #pragma unroll
        for (int mi = 0; mi < 4; mi++)
            #pragma unroll
            for (int ni = 0; ni < 4; ni++)
                #pragma unroll
                for (int i = 0; i < 4; i++) {
                    const int rw  = m0 + wm + mi * 16 + row_l + i;
                    const int cn = n0 + wn + ni * 16 + col_l;
                    C[(size_t)rw * 1024 + cn] = acc[mi][ni][i];
                }
    }
}

// ---------------------------------------------------------------------------
// Chunk-parallel scan, CT=32, NC=64. s_t = a_t*s_{t-1} + sigmoid(g)*k*v.
// 256-thread blocks = 4 independent wave-units (no intra-block sync needed).
// scan1: local scan per chunk; writes rounded kv product (kvb), chunk-local
// state Lc[ci][d] and decay product Pc[ci].
// ---------------------------------------------------------------------------
__global__ __launch_bounds__(256)
void scan1(const u16* __restrict__ Kq, const u16* __restrict__ Vq, const u16* __restrict__ Gq,
           const float* __restrict__ dec, u16* __restrict__ kvb,
           float* __restrict__ Lc, float* __restrict__ Pc)
{
    const int unit = blockIdx.x * 4 + (threadIdx.x >> 6);   // 0..4095
    const int d = threadIdx.x & 63;
    const int c = unit & (NC - 1), h = (unit >> 6) & 15, b = unit >> 10;
    const size_t t0 = (size_t)b * SEQ + c * CT;
    const size_t base = t0 * 1024 + h * 64 + d;
    const u16* kp = Kq + base;
    const u16* vp = Vq + base;
    const u16* gp = Gq + base;
    const float* dp = dec + t0 * 16 + h;
    float s = 0.f, P = 1.f;
    #pragma unroll 4
    for (int t = 0; t < CT; t++) {
        const size_t o = (size_t)t * 1024;
        const float a  = dp[t * 16];
        const u16 kq = f2bf(b2f(kp[o]) * b2f(vp[o]) * sigf(b2f(gp[o])));
        kvb[base + o] = kq;
        s = fmaf(a, s, b2f(kq));
        P *= a;
    }
    const int ci = (b * 16 + h) * NC + c;
    Lc[(size_t)ci * 64 + d] = s;
    if (d == 0) Pc[ci] = P;
}

// scan2 folded into scan3: each unit combines its chunk prefix inline.
__global__ __launch_bounds__(256)
void scan3(const u16* __restrict__ Qq, const u16* __restrict__ kvb,
           const float* __restrict__ dec,
           const float* __restrict__ Lc, const float* __restrict__ Pc,
           u16* __restrict__ attb)
{
    const int unit = blockIdx.x * 4 + (threadIdx.x >> 6);
    const int d = threadIdx.x & 63;
    const int c = unit & (NC - 1), h = (unit >> 6) & 15, b = unit >> 10;
    const size_t t0 = (size_t)b * SEQ + c * CT;
    const size_t base = t0 * 1024 + h * 64 + d;
    const u16* qp = Qq + base;
    const u16* kp = kvb + base;
    const float* dp = dec + t0 * 16 + h;

    // inline prefix combine over earlier chunks of this (b,h)
    const int ci0 = (b * 16 + h) * NC;
    float s = 0.f;
    for (int cc = 0; cc < c; cc++)
        s = fmaf(Pc[ci0 + cc], s, Lc[(size_t)(ci0 + cc) * 64 + d]);

    #pragma unroll 4
    for (int t = 0; t < CT; t++) {
        const size_t o = (size_t)t * 1024;
        const float a  = dp[t * 16];
        s = fmaf(a, s, b2f(kp[o]));
        attb[base + o] = f2bf(b2f(qp[o]) * s);
    }
}

// ---------------------------------------------------------------------------
// RMSNorm * rms_w * sigmoid(gpre) -> bf16. One wave per token (4 tokens per
// block), butterfly-only reduction, no LDS/syncthreads.
// ---------------------------------------------------------------------------
__global__ __launch_bounds__(256)
void rms_gate(const u16* __restrict__ attb, const u16* __restrict__ gpre,
              const float* __restrict__ rmsw, u16* __restrict__ o)
{
    const int wave = threadIdx.x >> 6, lane = threadIdx.x & 63;
    const size_t t = (size_t)blockIdx.x * 4 + wave;
    const ushort4* ap = (const ushort4*)(attb + t * 1024);
    ushort4 a4[4];
    float ss = 0.f;
    #pragma unroll
    for (int i = 0; i < 4; i++) {
        a4[i] = ap[lane + 64 * i];
        const float ax = b2f(a4[i].x), ay = b2f(a4[i].y);
        const float az = b2f(a4[i].z), aw = b2f(a4[i].w);
        ss += ax*ax + ay*ay + az*az + aw*aw;
    }
    #pragma unroll
    for (int off = 32; off > 0; off >>= 1) ss += __shfl_xor(ss, off);
    const float scale = rsqrtf(ss * (1.0f / 1024.0f) + 1.1920929e-7f);
    const ushort4* gp = (const ushort4*)(gpre + t * 1024);
    const float4*  wp = (const float4*)rmsw;
    uint2* op = (uint2*)(o + t * 1024);
    #pragma unroll
    for (int i = 0; i < 4; i++) {
        const ushort4 g4 = gp[lane + 64 * i];
        const float4  w  = wp[lane + 64 * i];
        __align__(8) u16 r[4];
        r[0] = f2bf(b2f(a4[i].x) * scale * w.x * sigf(b2f(g4.x)));
        r[1] = f2bf(b2f(a4[i].y) * scale * w.y * sigf(b2f(g4.y)));
        r[2] = f2bf(b2f(a4[i].z) * scale * w.z * sigf(b2f(g4.z)));
        r[3] = f2bf(b2f(a4[i].w) * scale * w.w * sigf(b2f(g4.w)));
        op[lane + 64 * i] = *(const uint2*)r;
    }
}

// ---------------------------------------------------------------------------
extern "C" void kernel_launch(void* const* d_in, const int* in_sizes, int n_in,
                              void* d_out, int out_size, void* d_ws, size_t ws_size,
                              hipStream_t stream)
{
    const float* x    = (const float*)d_in[0];
    const float* qU   = (const float*)d_in[1];
    const float* qV   = (const float*)d_in[2];
    const float* kU   = (const float*)d_in[3];
    const float* kV   = (const float*)d_in[4];
    const float* vU   = (const float*)d_in[5];
    const float* vV   = (const float*)d_in[6];
    const float* ql   = (const float*)d_in[7];
    const float* kl   = (const float*)d_in[8];
    const float* vl   = (const float*)d_in[9];
    const float* gl   = (const float*)d_in[10];
    const float* dw   = (const float*)d_in[11];
    const float* db   = (const float*)d_in[12];
    const float* ogw  = (const float*)d_in[13];
    const float* opw  = (const float*)d_in[14];
    const float* rmsw = (const float*)d_in[15];

    // workspace layout (byte offsets, ~165.2 MB total)
    char* w = (char*)d_ws;
    float* dec  = (float*)(w + 0);           // 512 KB
    u16*   WT   = (u16*)  (w + 524288);      // 5 slices x 2 MB (slice4 = ogwb)
    u16*   xb   = (u16*)  (w + 11010048);    // 16 MB
    u16*   opwb = (u16*)  (w + 27787264);    // 2 MB
    u16*   QKVG = (u16*)  (w + 29884416);    // 5 slices x 16 MB (q,k,v,g,gpre)
    u16*   RMSO = (u16*)  (w + 113770496);   // 16 MB
    u16*   ATTb = (u16*)  (w + 130547712);   // 16 MB
    u16*   kvb  = (u16*)  (w + 147324928);   // 16 MB
    float* Lc   = (float*)(w + 164102144);   // 1 MB
    float* Pc   = (float*)(w + 165150720);   // 16 KB
    // gU/gVT alias the QKVG region (consumed by weff-gemm before QKVG written)
    u16*   gU   = QKVG;                      // 8 MB
    u16*   gVT  = QKVG + 4194304;            // 8 MB
    u16*   ogwb = WT + 4 * 1048576;          // WT slice 4
    u16*   GPRE = QKVG + 4 * 8388608;        // QKVG slice 4

    // 1. prep: x cast + decay fused (x row in regs), weight casts, gathers
    prep<<<6144, 256, 0, stream>>>(x, ogw, opw, qU, kU, vU, qV, kV, vV,
                                   ql, kl, vl, gl, dw, db,
                                   xb, ogwb, opwb, gU, gVT, dec);

    // 2. WT[p][o][d] = sum_k gVT[p][o,k] * gU[p][d,k]  (= W_eff^T)
    mfma_gemm64<<<dim3(16, 16, 4), 256, 0, stream>>>(gVT, gU, WT);

    // 3. q,k,v,gate,gpre = x @ {W_eff_p, out_gate_w}^T -> bf16, z=5 batch
    //    256^2-tile 8-phase counted-vmcnt kernel (T2+T3+T4+T5).
    mfma_gemm256<<<640, 512, 0, stream>>>(xb, WT, QKVG);

    // 4-5. chunk-parallel scan (prefix combine inlined in scan3)
    scan1<<<1024, 256, 0, stream>>>(QKVG + 8388608, QKVG + 16777216, QKVG + 25165824,
                                    dec, kvb, Lc, Pc);
    scan3<<<1024, 256, 0, stream>>>(QKVG, kvb, dec, Lc, Pc, ATTb);

    // 6. rmsnorm * gate
    rms_gate<<<2048, 256, 0, stream>>>(ATTb, GPRE, rmsw, RMSO);

    // 7. final: rmso @ out_proj_w^T -> fp32 d_out
    mfma_gemm<0><<<dim3(8, 64, 1), 256, 0, stream>>>(RMSO, opwb, (float*)d_out, 0, 0, 0);
}

// Round 2
// 396.723 us; speedup vs baseline: 1.0050x; 1.0050x over previous
//
#include <hip/hip_runtime.h>
#include <hip/hip_bf16.h>

// Problem constants (B=4, S=2048, D_MODEL=1024, H=16, DH=64, RANK=256, NPRIM=16, top_k=4)
#define TOK 8192
#define SEQ 2048
#define CT  32          // scan chunk length
#define NC  64          // chunks per sequence

typedef __attribute__((ext_vector_type(8))) short bf16x8;   // 8 bf16 = 4 VGPRs
typedef __attribute__((ext_vector_type(4))) float f32x4;
typedef unsigned short u16;
typedef unsigned int   u32;

__device__ __forceinline__ u16 f2bf(float f) {
    u32 u = __float_as_uint(f);
    u = (u + 0x7FFFu + ((u >> 16) & 1u)) >> 16;   // RNE
    return (u16)u;
}
__device__ __forceinline__ float b2f(u16 h) { return __uint_as_float(((u32)h) << 16); }
__device__ __forceinline__ float sigf(float z) { return 1.f / (1.f + __expf(-z)); }

// Top-4 of 16 logits + softmax over the kept 4 (== softmax->topk->renorm, exact).
__device__ __forceinline__ void topk4(const float* __restrict__ lg, int* idx, float* wv)
{
    float v[16];
    #pragma unroll
    for (int i = 0; i < 16; i++) v[i] = lg[i];
    bool used[16];
    #pragma unroll
    for (int i = 0; i < 16; i++) used[i] = false;
    float val[4];
    #pragma unroll
    for (int k = 0; k < 4; k++) {
        int bi = 0; float bv = -3.0e38f;
        #pragma unroll
        for (int i = 0; i < 16; i++)
            if (!used[i] && v[i] > bv) { bv = v[i]; bi = i; }
        used[bi] = true; idx[k] = bi; val[k] = bv;
    }
    float e[4], s = 0.f;
    #pragma unroll
    for (int k = 0; k < 4; k++) { e[k] = expf(val[k] - val[0]); s += e[k]; }
    #pragma unroll
    for (int k = 0; k < 4; k++) wv[k] = e[k] / s;
}

// ---------------------------------------------------------------------------
// prep: one dispatch, branch by block range.
//   [0, 2048)    : x cast -> bf16 AND decay dec[t][h] (x row held in regs)
//   [2048, 3072) : out_gate_w cast
//   [3072, 4096) : out_proj_w cast
//   [4096, 6144) : gather selected prims -> gU (w folded), gVT (transposed)
// ---------------------------------------------------------------------------
__global__ __launch_bounds__(256)
void prep(const float* __restrict__ x, const float* __restrict__ ogw,
          const float* __restrict__ opw,
          const float* __restrict__ qU, const float* __restrict__ kU,
          const float* __restrict__ vU,
          const float* __restrict__ qV, const float* __restrict__ kV,
          const float* __restrict__ vV,
          const float* __restrict__ ql, const float* __restrict__ kl,
          const float* __restrict__ vl, const float* __restrict__ gl,
          const float* __restrict__ dw, const float* __restrict__ db,
          u16* __restrict__ xb, u16* __restrict__ ogwb, u16* __restrict__ opwb,
          u16* __restrict__ gU, u16* __restrict__ gVT, float* __restrict__ dec)
{
    const int blk = blockIdx.x;
    const int tid = threadIdx.x;

    if (blk < 2048) {
        // ---- x cast + decay: one wave per token ----
        const int wave = tid >> 6, lane = tid & 63;
        const int t = blk * 4 + wave;
        const float4* x4 = (const float4*)(x + (size_t)t * 1024);
        float4 xv[4];
        #pragma unroll
        for (int i = 0; i < 4; i++) xv[i] = x4[lane + 64 * i];
        // cast-store the row
        uint2* xrow = (uint2*)(xb + (size_t)t * 1024);
        #pragma unroll
        for (int i = 0; i < 4; i++) {
            __align__(8) u16 tq[4] = { f2bf(xv[i].x), f2bf(xv[i].y),
                                       f2bf(xv[i].z), f2bf(xv[i].w) };
            xrow[lane + 64 * i] = *(const uint2*)tq;
        }
        // 16 head dots from the same registers
        float p[16];
        #pragma unroll
        for (int h = 0; h < 16; h++) {
            const float4* w4 = (const float4*)(dw + (size_t)h * 1024);
            float s = 0.f;
            #pragma unroll
            for (int i = 0; i < 4; i++) {
                const float4 wv = w4[lane + 64 * i];
                s = fmaf(xv[i].x, wv.x, fmaf(xv[i].y, wv.y,
                    fmaf(xv[i].z, wv.z, fmaf(xv[i].w, wv.w, s))));
            }
            p[h] = s;
        }
        #pragma unroll
        for (int off = 32; off > 0; off >>= 1)
            #pragma unroll
            for (int h = 0; h < 16; h++) p[h] += __shfl_xor(p[h], off);
        if (lane == 0) {
            #pragma unroll
            for (int h = 0; h < 16; h++)
                dec[(size_t)t * 16 + h] = 1.f / (1.f + __expf(p[h] + db[h]));
        }
        return;
    }
    if (blk < 4096) {
        // ---- weight casts: 1 float4 per thread ----
        const float* src; u16* dst;
        int off;
        if (blk < 3072) { src = ogw; dst = ogwb; off = (blk - 2048) * 256 + tid; }
        else            { src = opw; dst = opwb; off = (blk - 3072) * 256 + tid; }
        const float4 v = ((const float4*)src)[off];
        __align__(8) u16 t[4] = { f2bf(v.x), f2bf(v.y), f2bf(v.z), f2bf(v.w) };
        ((uint2*)dst)[off] = *(const uint2*)t;
        return;
    }
    // ---- gather (topk inline, exact) ----
    {
        const int local = blk - 4096;
        const int z = local >> 8;              // 0..7
        const int bx = local & 15, by = (local >> 4) & 15;
        const int p = z & 3;
        const float* lg = (p == 0) ? ql : (p == 1) ? kl : (p == 2) ? vl : gl;
        int idx[4]; float wsel[4];
        topk4(lg, idx, wsel);

        if (z < 4) {
            // V^T gather: gVT[p][o][k=s*256+r] = V_sel[s][r][o]
            const float* V = (p == 0) ? qV : (p == 1) ? kV : vV;
            const int o0 = bx * 64, k0 = by * 64;
            const int s = k0 >> 8, r0 = k0 & 255;
            const float* Vb = V + (size_t)idx[s] * (256 * 1024);
            __shared__ float tile[64][68];
            const int rr = tid >> 4, cc = (tid & 15) << 2;
            #pragma unroll
            for (int i = 0; i < 4; i++) {
                const float4 v = *(const float4*)(Vb + (size_t)(r0 + rr + 16 * i) * 1024 + o0 + cc);
                *(float4*)&tile[rr + 16 * i][cc] = v;
            }
            __syncthreads();
            const int oo = tid >> 4, kk = (tid & 15) << 2;
            u16* out = gVT + (size_t)p * 1048576;
            #pragma unroll
            for (int i = 0; i < 4; i++) {
                __align__(8) u16 t[4];
                #pragma unroll
                for (int j = 0; j < 4; j++) t[j] = f2bf(tile[kk + j][oo + 16 * i]);
                *(uint2*)(out + (size_t)(o0 + oo + 16 * i) * 1024 + k0 + kk) = *(const uint2*)t;
            }
        } else {
            // U gather: gU[p][d][k=s*256+r] = w_s * U_sel[s][d][r]
            const float* U = (p == 0) ? qU : (p == 1) ? kU : vU;
            const int d0 = bx * 64, k0 = by * 64;
            const int s = k0 >> 8, r0 = k0 & 255;
            const float* Ub = U + (size_t)idx[s] * (1024 * 256);
            const float wq = wsel[s];
            u16* out = gU + (size_t)p * 1048576;
            const int rr = tid >> 4, cc = (tid & 15) << 2;
            #pragma unroll
            for (int i = 0; i < 4; i++) {
                const float4 v = *(const float4*)(Ub + (size_t)(d0 + rr + 16 * i) * 256 + r0 + cc);
                __align__(8) u16 t[4] = { f2bf(v.x * wq), f2bf(v.y * wq),
                                          f2bf(v.z * wq), f2bf(v.w * wq) };
                *(uint2*)(out + (size_t)(d0 + rr + 16 * i) * 1024 + k0 + cc) = *(const uint2*)t;
            }
        }
    }
}

// ---------------------------------------------------------------------------
// 64x64-tile bf16 MFMA GEMM for W_eff^T: C[m][n] = sum_k A[m,k]*B[n,k],
// M=N=K=1024, z batches slices of 1M elements. grid (16,16,4) -> 4 blocks/CU.
// ---------------------------------------------------------------------------
__global__ __launch_bounds__(256)
void mfma_gemm64(const u16* __restrict__ Asrc, const u16* __restrict__ Bsrc,
                 u16* __restrict__ Cout)
{
    __shared__ u16 As[64 * 64];
    __shared__ u16 Bs[64 * 64];
    const int z = blockIdx.z;
    const u16* A = Asrc + (size_t)z * 1048576;
    const u16* B = Bsrc + (size_t)z * 1048576;
    u16* C = Cout + (size_t)z * 1048576;
    const int tid = threadIdx.x, lane = tid & 63, wave = tid >> 6;
    const int m0 = blockIdx.y * 64, n0 = blockIdx.x * 64;
    const int wn = wave * 16;

    f32x4 acc[4];
    #pragma unroll
    for (int i = 0; i < 4; i++) acc[i] = (f32x4)0.f;

    for (int k0 = 0; k0 < 1024; k0 += 64) {
        __syncthreads();
        #pragma unroll
        for (int it = 0; it < 2; it++) {
            const int c   = it * 256 + tid;
            const int row = c >> 3, j = c & 7;
            const int g   = j ^ (row & 7);
            const u16* ga = A + (size_t)(m0 + row) * 1024 + k0 + g * 8;
            __builtin_amdgcn_global_load_lds(
                (const __attribute__((address_space(1))) u32*)ga,
                (__attribute__((address_space(3))) u32*)&As[(it * 256 + wave * 64) * 8],
                16, 0, 0);
            const u16* gb = B + (size_t)(n0 + row) * 1024 + k0 + g * 8;
            __builtin_amdgcn_global_load_lds(
                (const __attribute__((address_space(1))) u32*)gb,
                (__attribute__((address_space(3))) u32*)&Bs[(it * 256 + wave * 64) * 8],
                16, 0, 0);
        }
        __syncthreads();
        #pragma unroll
        for (int ks = 0; ks < 2; ks++) {
            const int gk = ks * 4 + (lane >> 4);
            const int rn = wn + (lane & 15);
            const int jb = gk ^ (rn & 7);
            const bf16x8 bfr = *(const bf16x8*)&Bs[rn * 64 + jb * 8];
            #pragma unroll
            for (int mi = 0; mi < 4; mi++) {
                const int rm = mi * 16 + (lane & 15);
                const int ja = gk ^ (rm & 7);
                const bf16x8 af = *(const bf16x8*)&As[rm * 64 + ja * 8];
                acc[mi] = __builtin_amdgcn_mfma_f32_16x16x32_bf16(af, bfr, acc[mi], 0, 0, 0);
            }
        }
    }
    const int col_l = lane & 15, row_l = (lane >> 4) * 4;
    #pragma unroll
    for (int mi = 0; mi < 4; mi++)
        #pragma unroll
        for (int i = 0; i < 4; i++)
            C[(size_t)(m0 + mi * 16 + row_l + i) * 1024 + n0 + wn + col_l] = f2bf(acc[mi][i]);
}

// ---------------------------------------------------------------------------
// 256x256-tile 8-phase bf16 MFMA GEMM (T2+T3+T4+T5 stack, m201 template).
// M=8192, N=1024, K=1024, z in {0..4} from the block decode. A (xb) shared
// across z; B/C z-strided.
//
// Geometry: 512 threads = 8 waves (2M x 4N); per-wave C = 128x64 = acc[8][4].
// LDS: [2 buf][A,B][2 half][128x64 bf16] = 128 KiB -> 1 block/CU, 2 waves/SIMD.
// Halves are quadrant-aligned; each LDS region's last read phase is unique:
//   A-h0: ph1   B-h0: ph1   B-h1: ph2   A-h1: ph3   (regs reused after).
// Stage issue (after the freeing phase's end barrier):
//   ph1: A-h1(t+1), B-h1(t+1)   ph2: A-h0(t+2)   ph4: B-h0(t+2)
// Counted waits: vmcnt(8) at ph1-end and ph4-end; never 0 in the main loop.
//
// ROUND-1 FIX: barriers are __builtin_amdgcn_s_barrier() and waitcnts are
// clobber-free asm + sched_barrier(0). The previous asm("s_barrier":::"memory")
// made the memory legalizer treat every barrier as a full fence -> implicit
// vmcnt(0) drain per phase -> 109.7us / 32% MfmaUtil (drain-limited regime,
// cf. m218 V1). Counted vmcnt must actually reach the ISA for T3/T4 to engage.
// REQUIRES grid == (640,1,1), 512 threads. 640%8==0 -> XCD decode bijective.
// ---------------------------------------------------------------------------
__global__ __launch_bounds__(512)
void mfma_gemm256(const u16* __restrict__ Asrc, const u16* __restrict__ Bt,
                  u16* __restrict__ Cout)
{
    __shared__ __align__(16) u16 Alds[2][2][8192];   // [buf][half(qm)][128*64]
    __shared__ __align__(16) u16 Blds[2][2][8192];   // [buf][half(qn)][128*64]

    const int flat  = blockIdx.x;
    const int xcd   = flat & 7;          // round-robin dispatch -> XCD id
    const int local = flat >> 3;         // 0..79, contiguous per XCD
    const int zb    = local >> 4;        // 0..4   (per-XCD: 16 blocks per z)
    const int rem   = local & 15;
    const int m0    = (xcd * 4 + (rem >> 2)) * 256;  // per-XCD A stripe: 2 MB
    const int n0    = (rem & 3) * 256;               // B slice: 2 MB

    const u16* A = Asrc;                               // shared across z
    const u16* B = Bt + (size_t)zb * 1048576;
    u16*       C = Cout + (size_t)zb * 8388608;

    const int tid  = threadIdx.x;
    const int lane = tid & 63, wave = tid >> 6;
    const int wmi  = wave >> 2, wni = wave & 3;        // 2 x 4 wave grid
    const int l15  = lane & 15, l4 = lane >> 4;

    f32x4 acc[8][4];
    #pragma unroll
    for (int i = 0; i < 8; i++)
        #pragma unroll
        for (int j = 0; j < 4; j++) acc[i][j] = (f32x4)0.f;

    bf16x8 a_fr[2][4];        // [ks][m-tile within quadrant]
    bf16x8 b_fr[2][2][2];     // [qn][ks][n-tile within quadrant]

// --- staging: linear LDS dest (wave-uniform base), swizzle on GLOBAL source.
#define STAGE_A(BUFP, HALF, T) do {                                           \
    _Pragma("unroll")                                                         \
    for (int it_ = 0; it_ < 2; it_++) {                                       \
        const int bc_ = it_ * 512 + wave * 64;                                \
        const int c_  = bc_ + lane;                                           \
        const int r_  = c_ >> 3, j_ = c_ & 7;                                 \
        const int g_  = j_ ^ (r_ & 7);                                        \
        const int gr_ = m0 + ((r_ >> 6) << 7) + (HALF) * 64 + (r_ & 63);      \
        const u16* ga_ = A + (size_t)gr_ * 1024 + (T) * 64 + g_ * 8;          \
        __builtin_amdgcn_global_load_lds(                                     \
            (const __attribute__((address_space(1))) u32*)ga_,                \
            (__attribute__((address_space(3))) u32*)&(BUFP)[(HALF)][bc_ * 8], \
            16, 0, 0);                                                        \
    } } while (0)

#define STAGE_B(BUFP, HALF, T) do {                                           \
    _Pragma("unroll")                                                         \
    for (int it_ = 0; it_ < 2; it_++) {                                       \
        const int bc_ = it_ * 512 + wave * 64;                                \
        const int c_  = bc_ + lane;                                           \
        const int r_  = c_ >> 3, j_ = c_ & 7;                                 \
        const int g_  = j_ ^ (r_ & 7);                                        \
        const int gr_ = n0 + ((r_ >> 5) << 6) + (HALF) * 32 + (r_ & 31);      \
        const u16* gb_ = B + (size_t)gr_ * 1024 + (T) * 64 + g_ * 8;          \
        __builtin_amdgcn_global_load_lds(                                     \
            (const __attribute__((address_space(1))) u32*)gb_,                \
            (__attribute__((address_space(3))) u32*)&(BUFP)[(HALF)][bc_ * 8], \
            16, 0, 0);                                                        \
    } } while (0)

#define READ_A(BUFP, QM) do {                                                 \
    _Pragma("unroll") for (int ks_ = 0; ks_ < 2; ks_++)                       \
    _Pragma("unroll") for (int m4_ = 0; m4_ < 4; m4_++) {                     \
        const int r_  = wmi * 64 + m4_ * 16 + l15;                            \
        const int gk_ = ks_ * 4 + l4;                                         \
        a_fr[ks_][m4_] =                                                      \
            *(const bf16x8*)&(BUFP)[QM][r_ * 64 + ((gk_ ^ (r_ & 7)) * 8)];    \
    } } while (0)

#define READ_B(BUFP, QN) do {                                                 \
    _Pragma("unroll") for (int ks_ = 0; ks_ < 2; ks_++)                       \
    _Pragma("unroll") for (int n2_ = 0; n2_ < 2; n2_++) {                     \
        const int r_  = wni * 32 + n2_ * 16 + l15;                            \
        const int gk_ = ks_ * 4 + l4;                                         \
        b_fr[QN][ks_][n2_] =                                                  \
            *(const bf16x8*)&(BUFP)[QN][r_ * 64 + ((gk_ ^ (r_ & 7)) * 8)];    \
    } } while (0)

#define MFMA_PH(QM, QN) do {                                                  \
    __builtin_amdgcn_s_setprio(1);                                            \
    _Pragma("unroll") for (int ks_ = 0; ks_ < 2; ks_++)                       \
    _Pragma("unroll") for (int m4_ = 0; m4_ < 4; m4_++)                       \
    _Pragma("unroll") for (int n2_ = 0; n2_ < 2; n2_++)                       \
        acc[(QM) * 4 + m4_][(QN) * 2 + n2_] =                                 \
            __builtin_amdgcn_mfma_f32_16x16x32_bf16(                          \
                a_fr[ks_][m4_], b_fr[QN][ks_][n2_],                           \
                acc[(QM) * 4 + m4_][(QN) * 2 + n2_], 0, 0, 0);                \
    __builtin_amdgcn_s_setprio(0);                                            \
} while (0)

// Template-faithful sync: builtin barrier (no fence), clobber-free counted
// vmcnt pinned with sched_barrier(0) (rule #18 analog).
#define BAR()    __builtin_amdgcn_s_barrier()
#define VMCNT8() do { __asm__ volatile("s_waitcnt vmcnt(8)");                 \
                      __builtin_amdgcn_sched_barrier(0); } while (0)
#define VMCNT4() do { __asm__ volatile("s_waitcnt vmcnt(4)");                 \
                      __builtin_amdgcn_sched_barrier(0); } while (0)
#define VMCNT0() do { __asm__ volatile("s_waitcnt vmcnt(0)");                 \
                      __builtin_amdgcn_sched_barrier(0); } while (0)

    // prologue: issue order fixes the per-wave vmcnt ledger:
    //   [A0h0 B0h0 A0h1 B0h1 A1h0 B1h0] = 12 loads; vmcnt(8) completes A0h0,B0h0.
    STAGE_A(Alds[0], 0, 0);
    STAGE_B(Blds[0], 0, 0);
    STAGE_A(Alds[0], 1, 0);
    STAGE_B(Blds[0], 1, 0);
    STAGE_A(Alds[1], 0, 1);
    STAGE_B(Blds[1], 0, 1);
    VMCNT8(); BAR();

    #pragma unroll 1
    for (int t = 0; t < 16; ++t) {
        const int b = t & 1, nb = b ^ 1;
        u16 (*Ab)[8192] = Alds[b];
        u16 (*Bb)[8192] = Blds[b];

        // ---- phase 1: quadrant (0,0) ----
        READ_A(Ab, 0);
        READ_B(Bb, 0);
        if (t + 1 < 16) { STAGE_A(Alds[nb], 1, t + 1); STAGE_B(Blds[nb], 1, t + 1); }
        BAR();
        MFMA_PH(0, 0);
        if (t < 15) { VMCNT8(); } else { VMCNT0(); }   // completes A-h1(t),B-h1(t)
        BAR();

        // ---- phase 2: quadrant (0,1) ----  (a_fr reused)
        READ_B(Bb, 1);
        if (t + 2 < 16) STAGE_A(Alds[b], 0, t + 2);    // A-h0(b) freed at ph1-end
        BAR();
        MFMA_PH(0, 1);
        BAR();

        // ---- phase 3: quadrant (1,0) ----  (b_fr[0] reused)
        READ_A(Ab, 1);
        BAR();
        MFMA_PH(1, 0);
        BAR();

        // ---- phase 4: quadrant (1,1) ----  (a_fr + b_fr[1] reused)
        if (t + 2 < 16) STAGE_B(Blds[b], 0, t + 2);    // B-h0(b) freed at ph1-end
        BAR();
        MFMA_PH(1, 1);
        if (t + 2 < 16)      { VMCNT8(); }             // completes A-h0(t+1),B-h0(t+1)
        else if (t + 1 < 16) { VMCNT4(); }             // t==14 tail
        BAR();
    }

#undef STAGE_A
#undef STAGE_B
#undef READ_A
#undef READ_B
#undef MFMA_PH
#undef BAR
#undef VMCNT8
#undef VMCNT4
#undef VMCNT0

    // epilogue: C/D layout col=lane&15, row=(lane>>4)*4+reg  [m89-verified]
    const int col_l = lane & 15, row_l = (lane >> 4) * 4;
    #pragma unroll
    for (int mi = 0; mi < 8; mi++)
        #pragma unroll
        for (int ni = 0; ni < 4; ni++)
            #pragma unroll
            for (int i = 0; i < 4; i++) {
                const int rw = m0 + wmi * 128 + mi * 16 + row_l + i;
                const int cn = n0 + wni * 64 + ni * 16 + col_l;
                C[(size_t)rw * 1024 + cn] = f2bf(acc[mi][ni][i]);
            }
}

// ---------------------------------------------------------------------------
// 128x128-tile bf16 MFMA GEMM, M=8192, N=K=1024, z-batched. XCD-swizzled
// block decode (flat%8 = XCD under round-robin) pins an 8-row m-group per
// XCD: per-z working set A 2MB + B 2MB fits the 4MB XCD L2.
// REQUIRES grid == (8, 64, Z).  (Kept for the final fp32-out projection.)
// ---------------------------------------------------------------------------
template<int OUTBF>
__global__ __launch_bounds__(256)
void mfma_gemm(const u16* __restrict__ Asrc, const u16* __restrict__ Bt,
               void* __restrict__ Cout, size_t astride, size_t bstride, size_t cstride)
{
    __shared__ u16 As[128 * 64];
    __shared__ u16 Bs[128 * 64];
    const int flat = blockIdx.x + 8 * (blockIdx.y + 64 * blockIdx.z);
    const int xcd = flat & 7;
    const int r   = flat >> 3;
    const int nb = r & 7, mlocal = (r >> 3) & 7, zb = r >> 6;
    const int m0 = (xcd * 8 + mlocal) * 128, n0 = nb * 128;

    const u16* A = Asrc + (size_t)zb * astride;
    const u16* B = Bt   + (size_t)zb * bstride;
    const int tid  = threadIdx.x;
    const int lane = tid & 63, wave = tid >> 6;
    const int wm = (wave >> 1) * 64, wn = (wave & 1) * 64;

    f32x4 acc[4][4];
    #pragma unroll
    for (int i = 0; i < 4; i++)
        #pragma unroll
        for (int j = 0; j < 4; j++) acc[i][j] = (f32x4)0.f;

    for (int k0 = 0; k0 < 1024; k0 += 64) {
        __syncthreads();
        #pragma unroll
        for (int it = 0; it < 4; it++) {
            const int c   = it * 256 + tid;
            const int row = c >> 3, j = c & 7;
            const int g   = j ^ (row & 7);
            const u16* ga = A + (size_t)(m0 + row) * 1024 + k0 + g * 8;
            __builtin_amdgcn_global_load_lds(
                (const __attribute__((address_space(1))) u32*)ga,
                (__attribute__((address_space(3))) u32*)&As[(it * 256 + wave * 64) * 8],
                16, 0, 0);
            const u16* gb = B + (size_t)(n0 + row) * 1024 + k0 + g * 8;
            __builtin_amdgcn_global_load_lds(
                (const __attribute__((address_space(1))) u32*)gb,
                (__attribute__((address_space(3))) u32*)&Bs[(it * 256 + wave * 64) * 8],
                16, 0, 0);
        }
        __syncthreads();
        #pragma unroll
        for (int ks = 0; ks < 2; ks++) {
            bf16x8 af[4], bfr[4];
            const int gk = ks * 4 + (lane >> 4);
            #pragma unroll
            for (int mi = 0; mi < 4; mi++) {
                const int rr  = wm + mi * 16 + (lane & 15);
                const int ja = gk ^ (rr & 7);
                af[mi] = *(const bf16x8*)&As[rr * 64 + ja * 8];
                const int rn = wn + mi * 16 + (lane & 15);
                const int jb = gk ^ (rn & 7);
                bfr[mi] = *(const bf16x8*)&Bs[rn * 64 + jb * 8];
            }
            #pragma unroll
            for (int mi = 0; mi < 4; mi++)
                #pragma unroll
                for (int ni = 0; ni < 4; ni++)
                    acc[mi][ni] = __builtin_amdgcn_mfma_f32_16x16x32_bf16(
                        af[mi], bfr[ni], acc[mi][ni], 0, 0, 0);
        }
    }
    // epilogue: C/D layout col=lane&15, row=(lane>>4)*4+reg  [m89-verified]
    const int col_l = lane & 15, row_l = (lane >> 4) * 4;
    if (OUTBF) {
        u16* C = (u16*)Cout + (size_t)zb * cstride;
        #pragma unroll
        for (int mi = 0; mi < 4; mi++)
            #pragma unroll
            for (int ni = 0; ni < 4; ni++)
                #pragma unroll
                for (int i = 0; i < 4; i++) {
                    const int rw  = m0 + wm + mi * 16 + row_l + i;
                    const int cn = n0 + wn + ni * 16 + col_l;
                    C[(size_t)rw * 1024 + cn] = f2bf(acc[mi][ni][i]);
                }
    } else {
        float* C = (float*)Cout + (size_t)zb * cstride;
        #pragma unroll
        for (int mi = 0; mi < 4; mi++)
            #pragma unroll
            for (int ni = 0; ni < 4; ni++)
                #pragma unroll
                for (int i = 0; i < 4; i++) {
                    const int rw  = m0 + wm + mi * 16 + row_l + i;
                    const int cn = n0 + wn + ni * 16 + col_l;
                    C[(size_t)rw * 1024 + cn] = acc[mi][ni][i];
                }
    }
}

// ---------------------------------------------------------------------------
// Chunk-parallel scan, CT=32, NC=64. s_t = a_t*s_{t-1} + sigmoid(g)*k*v.
// 256-thread blocks = 4 independent wave-units (no intra-block sync needed).
// scan1: local scan per chunk; writes rounded kv product (kvb), chunk-local
// state Lc[ci][d] and decay product Pc[ci].
// ---------------------------------------------------------------------------
__global__ __launch_bounds__(256)
void scan1(const u16* __restrict__ Kq, const u16* __restrict__ Vq, const u16* __restrict__ Gq,
           const float* __restrict__ dec, u16* __restrict__ kvb,
           float* __restrict__ Lc, float* __restrict__ Pc)
{
    const int unit = blockIdx.x * 4 + (threadIdx.x >> 6);   // 0..4095
    const int d = threadIdx.x & 63;
    const int c = unit & (NC - 1), h = (unit >> 6) & 15, b = unit >> 10;
    const size_t t0 = (size_t)b * SEQ + c * CT;
    const size_t base = t0 * 1024 + h * 64 + d;
    const u16* kp = Kq + base;
    const u16* vp = Vq + base;
    const u16* gp = Gq + base;
    const float* dp = dec + t0 * 16 + h;
    float s = 0.f, P = 1.f;
    #pragma unroll 4
    for (int t = 0; t < CT; t++) {
        const size_t o = (size_t)t * 1024;
        const float a  = dp[t * 16];
        const u16 kq = f2bf(b2f(kp[o]) * b2f(vp[o]) * sigf(b2f(gp[o])));
        kvb[base + o] = kq;
        s = fmaf(a, s, b2f(kq));
        P *= a;
    }
    const int ci = (b * 16 + h) * NC + c;
    Lc[(size_t)ci * 64 + d] = s;
    if (d == 0) Pc[ci] = P;
}

// scan2 folded into scan3: each unit combines its chunk prefix inline.
__global__ __launch_bounds__(256)
void scan3(const u16* __restrict__ Qq, const u16* __restrict__ kvb,
           const float* __restrict__ dec,
           const float* __restrict__ Lc, const float* __restrict__ Pc,
           u16* __restrict__ attb)
{
    const int unit = blockIdx.x * 4 + (threadIdx.x >> 6);
    const int d = threadIdx.x & 63;
    const int c = unit & (NC - 1), h = (unit >> 6) & 15, b = unit >> 10;
    const size_t t0 = (size_t)b * SEQ + c * CT;
    const size_t base = t0 * 1024 + h * 64 + d;
    const u16* qp = Qq + base;
    const u16* kp = kvb + base;
    const float* dp = dec + t0 * 16 + h;

    // inline prefix combine over earlier chunks of this (b,h)
    const int ci0 = (b * 16 + h) * NC;
    float s = 0.f;
    for (int cc = 0; cc < c; cc++)
        s = fmaf(Pc[ci0 + cc], s, Lc[(size_t)(ci0 + cc) * 64 + d]);

    #pragma unroll 4
    for (int t = 0; t < CT; t++) {
        const size_t o = (size_t)t * 1024;
        const float a  = dp[t * 16];
        s = fmaf(a, s, b2f(kp[o]));
        attb[base + o] = f2bf(b2f(qp[o]) * s);
    }
}

// ---------------------------------------------------------------------------
// RMSNorm * rms_w * sigmoid(gpre) -> bf16. One wave per token (4 tokens per
// block), butterfly-only reduction, no LDS/syncthreads.
// ---------------------------------------------------------------------------
__global__ __launch_bounds__(256)
void rms_gate(const u16* __restrict__ attb, const u16* __restrict__ gpre,
              const float* __restrict__ rmsw, u16* __restrict__ o)
{
    const int wave = threadIdx.x >> 6, lane = threadIdx.x & 63;
    const size_t t = (size_t)blockIdx.x * 4 + wave;
    const ushort4* ap = (const ushort4*)(attb + t * 1024);
    ushort4 a4[4];
    float ss = 0.f;
    #pragma unroll
    for (int i = 0; i < 4; i++) {
        a4[i] = ap[lane + 64 * i];
        const float ax = b2f(a4[i].x), ay = b2f(a4[i].y);
        const float az = b2f(a4[i].z), aw = b2f(a4[i].w);
        ss += ax*ax + ay*ay + az*az + aw*aw;
    }
    #pragma unroll
    for (int off = 32; off > 0; off >>= 1) ss += __shfl_xor(ss, off);
    const float scale = rsqrtf(ss * (1.0f / 1024.0f) + 1.1920929e-7f);
    const ushort4* gp = (const ushort4*)(gpre + t * 1024);
    const float4*  wp = (const float4*)rmsw;
    uint2* op = (uint2*)(o + t * 1024);
    #pragma unroll
    for (int i = 0; i < 4; i++) {
        const ushort4 g4 = gp[lane + 64 * i];
        const float4  w  = wp[lane + 64 * i];
        __align__(8) u16 r[4];
        r[0] = f2bf(b2f(a4[i].x) * scale * w.x * sigf(b2f(g4.x)));
        r[1] = f2bf(b2f(a4[i].y) * scale * w.y * sigf(b2f(g4.y)));
        r[2] = f2bf(b2f(a4[i].z) * scale * w.z * sigf(b2f(g4.z)));
        r[3] = f2bf(b2f(a4[i].w) * scale * w.w * sigf(b2f(g4.w)));
        op[lane + 64 * i] = *(const uint2*)r;
    }
}

// ---------------------------------------------------------------------------
extern "C" void kernel_launch(void* const* d_in, const int* in_sizes, int n_in,
                              void* d_out, int out_size, void* d_ws, size_t ws_size,
                              hipStream_t stream)
{
    const float* x    = (const float*)d_in[0];
    const float* qU   = (const float*)d_in[1];
    const float* qV   = (const float*)d_in[2];
    const float* kU   = (const float*)d_in[3];
    const float* kV   = (const float*)d_in[4];
    const float* vU   = (const float*)d_in[5];
    const float* vV   = (const float*)d_in[6];
    const float* ql   = (const float*)d_in[7];
    const float* kl   = (const float*)d_in[8];
    const float* vl   = (const float*)d_in[9];
    const float* gl   = (const float*)d_in[10];
    const float* dw   = (const float*)d_in[11];
    const float* db   = (const float*)d_in[12];
    const float* ogw  = (const float*)d_in[13];
    const float* opw  = (const float*)d_in[14];
    const float* rmsw = (const float*)d_in[15];

    // workspace layout (byte offsets, ~165.2 MB total)
    char* w = (char*)d_ws;
    float* dec  = (float*)(w + 0);           // 512 KB
    u16*   WT   = (u16*)  (w + 524288);      // 5 slices x 2 MB (slice4 = ogwb)
    u16*   xb   = (u16*)  (w + 11010048);    // 16 MB
    u16*   opwb = (u16*)  (w + 27787264);    // 2 MB
    u16*   QKVG = (u16*)  (w + 29884416);    // 5 slices x 16 MB (q,k,v,g,gpre)
    u16*   RMSO = (u16*)  (w + 113770496);   // 16 MB
    u16*   ATTb = (u16*)  (w + 130547712);   // 16 MB
    u16*   kvb  = (u16*)  (w + 147324928);   // 16 MB
    float* Lc   = (float*)(w + 164102144);   // 1 MB
    float* Pc   = (float*)(w + 165150720);   // 16 KB
    // gU/gVT alias the QKVG region (consumed by weff-gemm before QKVG written)
    u16*   gU   = QKVG;                      // 8 MB
    u16*   gVT  = QKVG + 4194304;            // 8 MB
    u16*   ogwb = WT + 4 * 1048576;          // WT slice 4
    u16*   GPRE = QKVG + 4 * 8388608;        // QKVG slice 4

    // 1. prep: x cast + decay fused (x row in regs), weight casts, gathers
    prep<<<6144, 256, 0, stream>>>(x, ogw, opw, qU, kU, vU, qV, kV, vV,
                                   ql, kl, vl, gl, dw, db,
                                   xb, ogwb, opwb, gU, gVT, dec);

    // 2. WT[p][o][d] = sum_k gVT[p][o,k] * gU[p][d,k]  (= W_eff^T)
    mfma_gemm64<<<dim3(16, 16, 4), 256, 0, stream>>>(gVT, gU, WT);

    // 3. q,k,v,gate,gpre = x @ {W_eff_p, out_gate_w}^T -> bf16, z=5 batch
    //    256^2-tile 8-phase counted-vmcnt kernel (T2+T3+T4+T5).
    mfma_gemm256<<<640, 512, 0, stream>>>(xb, WT, QKVG);

    // 4-5. chunk-parallel scan (prefix combine inlined in scan3)
    scan1<<<1024, 256, 0, stream>>>(QKVG + 8388608, QKVG + 16777216, QKVG + 25165824,
                                    dec, kvb, Lc, Pc);
    scan3<<<1024, 256, 0, stream>>>(QKVG, kvb, dec, Lc, Pc, ATTb);

    // 6. rmsnorm * gate
    rms_gate<<<2048, 256, 0, stream>>>(ATTb, GPRE, rmsw, RMSO);

    // 7. final: rmso @ out_proj_w^T -> fp32 d_out
    mfma_gemm<0><<<dim3(8, 64, 1), 256, 0, stream>>>(RMSO, opwb, (float*)d_out, 0, 0, 0);
}

// Round 3
// 390.136 us; speedup vs baseline: 1.0219x; 1.0169x over previous
//
#include <hip/hip_runtime.h>
#include <hip/hip_bf16.h>

// Problem constants (B=4, S=2048, D_MODEL=1024, H=16, DH=64, RANK=256, NPRIM=16, top_k=4)
#define TOK 8192
#define SEQ 2048
#define CT  32          // scan chunk length
#define NC  64          // chunks per sequence

typedef __attribute__((ext_vector_type(8))) short bf16x8;   // 8 bf16 = 4 VGPRs
typedef __attribute__((ext_vector_type(4))) float f32x4;
typedef unsigned short u16;
typedef unsigned int   u32;

__device__ __forceinline__ u16 f2bf(float f) {
    u32 u = __float_as_uint(f);
    u = (u + 0x7FFFu + ((u >> 16) & 1u)) >> 16;   // RNE
    return (u16)u;
}
__device__ __forceinline__ float b2f(u16 h) { return __uint_as_float(((u32)h) << 16); }
__device__ __forceinline__ float sigf(float z) { return 1.f / (1.f + __expf(-z)); }

// Inline-asm ds_read_b128: opaque to SIInsertWaitcnts' LDS-DMA alias tracking,
// so the compiler cannot attach a conservative vmcnt(0) to it (the r2 stall).
// Caller owns the lgkmcnt discipline (rule #18: lgkmcnt(0)+sched_barrier(0)
// before dependent MFMAs).
__device__ __forceinline__ bf16x8 dsr128(const u16* p) {
    bf16x8 r;
    const u32 a = (u32)(size_t)(const __attribute__((address_space(3))) u16*)p;
    __asm__ volatile("ds_read_b128 %0, %1" : "=v"(r) : "v"(a));
    return r;
}

// Top-4 of 16 logits + softmax over the kept 4 (== softmax->topk->renorm, exact).
__device__ __forceinline__ void topk4(const float* __restrict__ lg, int* idx, float* wv)
{
    float v[16];
    #pragma unroll
    for (int i = 0; i < 16; i++) v[i] = lg[i];
    bool used[16];
    #pragma unroll
    for (int i = 0; i < 16; i++) used[i] = false;
    float val[4];
    #pragma unroll
    for (int k = 0; k < 4; k++) {
        int bi = 0; float bv = -3.0e38f;
        #pragma unroll
        for (int i = 0; i < 16; i++)
            if (!used[i] && v[i] > bv) { bv = v[i]; bi = i; }
        used[bi] = true; idx[k] = bi; val[k] = bv;
    }
    float e[4], s = 0.f;
    #pragma unroll
    for (int k = 0; k < 4; k++) { e[k] = expf(val[k] - val[0]); s += e[k]; }
    #pragma unroll
    for (int k = 0; k < 4; k++) wv[k] = e[k] / s;
}

// ---------------------------------------------------------------------------
// prep: one dispatch, branch by block range.
//   [0, 2048)    : x cast -> bf16 AND decay dec[t][h] (x row held in regs)
//   [2048, 3072) : out_gate_w cast
//   [3072, 4096) : out_proj_w cast
//   [4096, 6144) : gather selected prims -> gU (w folded), gVT (transposed)
// ---------------------------------------------------------------------------
__global__ __launch_bounds__(256)
void prep(const float* __restrict__ x, const float* __restrict__ ogw,
          const float* __restrict__ opw,
          const float* __restrict__ qU, const float* __restrict__ kU,
          const float* __restrict__ vU,
          const float* __restrict__ qV, const float* __restrict__ kV,
          const float* __restrict__ vV,
          const float* __restrict__ ql, const float* __restrict__ kl,
          const float* __restrict__ vl, const float* __restrict__ gl,
          const float* __restrict__ dw, const float* __restrict__ db,
          u16* __restrict__ xb, u16* __restrict__ ogwb, u16* __restrict__ opwb,
          u16* __restrict__ gU, u16* __restrict__ gVT, float* __restrict__ dec)
{
    const int blk = blockIdx.x;
    const int tid = threadIdx.x;

    if (blk < 2048) {
        // ---- x cast + decay: one wave per token ----
        const int wave = tid >> 6, lane = tid & 63;
        const int t = blk * 4 + wave;
        const float4* x4 = (const float4*)(x + (size_t)t * 1024);
        float4 xv[4];
        #pragma unroll
        for (int i = 0; i < 4; i++) xv[i] = x4[lane + 64 * i];
        // cast-store the row
        uint2* xrow = (uint2*)(xb + (size_t)t * 1024);
        #pragma unroll
        for (int i = 0; i < 4; i++) {
            __align__(8) u16 tq[4] = { f2bf(xv[i].x), f2bf(xv[i].y),
                                       f2bf(xv[i].z), f2bf(xv[i].w) };
            xrow[lane + 64 * i] = *(const uint2*)tq;
        }
        // 16 head dots from the same registers
        float p[16];
        #pragma unroll
        for (int h = 0; h < 16; h++) {
            const float4* w4 = (const float4*)(dw + (size_t)h * 1024);
            float s = 0.f;
            #pragma unroll
            for (int i = 0; i < 4; i++) {
                const float4 wv = w4[lane + 64 * i];
                s = fmaf(xv[i].x, wv.x, fmaf(xv[i].y, wv.y,
                    fmaf(xv[i].z, wv.z, fmaf(xv[i].w, wv.w, s))));
            }
            p[h] = s;
        }
        #pragma unroll
        for (int off = 32; off > 0; off >>= 1)
            #pragma unroll
            for (int h = 0; h < 16; h++) p[h] += __shfl_xor(p[h], off);
        if (lane == 0) {
            #pragma unroll
            for (int h = 0; h < 16; h++)
                dec[(size_t)t * 16 + h] = 1.f / (1.f + __expf(p[h] + db[h]));
        }
        return;
    }
    if (blk < 4096) {
        // ---- weight casts: 1 float4 per thread ----
        const float* src; u16* dst;
        int off;
        if (blk < 3072) { src = ogw; dst = ogwb; off = (blk - 2048) * 256 + tid; }
        else            { src = opw; dst = opwb; off = (blk - 3072) * 256 + tid; }
        const float4 v = ((const float4*)src)[off];
        __align__(8) u16 t[4] = { f2bf(v.x), f2bf(v.y), f2bf(v.z), f2bf(v.w) };
        ((uint2*)dst)[off] = *(const uint2*)t;
        return;
    }
    // ---- gather (topk inline, exact) ----
    {
        const int local = blk - 4096;
        const int z = local >> 8;              // 0..7
        const int bx = local & 15, by = (local >> 4) & 15;
        const int p = z & 3;
        const float* lg = (p == 0) ? ql : (p == 1) ? kl : (p == 2) ? vl : gl;
        int idx[4]; float wsel[4];
        topk4(lg, idx, wsel);

        if (z < 4) {
            // V^T gather: gVT[p][o][k=s*256+r] = V_sel[s][r][o]
            const float* V = (p == 0) ? qV : (p == 1) ? kV : vV;
            const int o0 = bx * 64, k0 = by * 64;
            const int s = k0 >> 8, r0 = k0 & 255;
            const float* Vb = V + (size_t)idx[s] * (256 * 1024);
            __shared__ float tile[64][68];
            const int rr = tid >> 4, cc = (tid & 15) << 2;
            #pragma unroll
            for (int i = 0; i < 4; i++) {
                const float4 v = *(const float4*)(Vb + (size_t)(r0 + rr + 16 * i) * 1024 + o0 + cc);
                *(float4*)&tile[rr + 16 * i][cc] = v;
            }
            __syncthreads();
            const int oo = tid >> 4, kk = (tid & 15) << 2;
            u16* out = gVT + (size_t)p * 1048576;
            #pragma unroll
            for (int i = 0; i < 4; i++) {
                __align__(8) u16 t[4];
                #pragma unroll
                for (int j = 0; j < 4; j++) t[j] = f2bf(tile[kk + j][oo + 16 * i]);
                *(uint2*)(out + (size_t)(o0 + oo + 16 * i) * 1024 + k0 + kk) = *(const uint2*)t;
            }
        } else {
            // U gather: gU[p][d][k=s*256+r] = w_s * U_sel[s][d][r]
            const float* U = (p == 0) ? qU : (p == 1) ? kU : vU;
            const int d0 = bx * 64, k0 = by * 64;
            const int s = k0 >> 8, r0 = k0 & 255;
            const float* Ub = U + (size_t)idx[s] * (1024 * 256);
            const float wq = wsel[s];
            u16* out = gU + (size_t)p * 1048576;
            const int rr = tid >> 4, cc = (tid & 15) << 2;
            #pragma unroll
            for (int i = 0; i < 4; i++) {
                const float4 v = *(const float4*)(Ub + (size_t)(d0 + rr + 16 * i) * 256 + r0 + cc);
                __align__(8) u16 t[4] = { f2bf(v.x * wq), f2bf(v.y * wq),
                                          f2bf(v.z * wq), f2bf(v.w * wq) };
                *(uint2*)(out + (size_t)(d0 + rr + 16 * i) * 1024 + k0 + cc) = *(const uint2*)t;
            }
        }
    }
}

// ---------------------------------------------------------------------------
// 64x64-tile bf16 MFMA GEMM for W_eff^T: C[m][n] = sum_k A[m,k]*B[n,k],
// M=N=K=1024, z batches slices of 1M elements. grid (16,16,4) -> 4 blocks/CU.
// ---------------------------------------------------------------------------
__global__ __launch_bounds__(256)
void mfma_gemm64(const u16* __restrict__ Asrc, const u16* __restrict__ Bsrc,
                 u16* __restrict__ Cout)
{
    __shared__ u16 As[64 * 64];
    __shared__ u16 Bs[64 * 64];
    const int z = blockIdx.z;
    const u16* A = Asrc + (size_t)z * 1048576;
    const u16* B = Bsrc + (size_t)z * 1048576;
    u16* C = Cout + (size_t)z * 1048576;
    const int tid = threadIdx.x, lane = tid & 63, wave = tid >> 6;
    const int m0 = blockIdx.y * 64, n0 = blockIdx.x * 64;
    const int wn = wave * 16;

    f32x4 acc[4];
    #pragma unroll
    for (int i = 0; i < 4; i++) acc[i] = (f32x4)0.f;

    for (int k0 = 0; k0 < 1024; k0 += 64) {
        __syncthreads();
        #pragma unroll
        for (int it = 0; it < 2; it++) {
            const int c   = it * 256 + tid;
            const int row = c >> 3, j = c & 7;
            const int g   = j ^ (row & 7);
            const u16* ga = A + (size_t)(m0 + row) * 1024 + k0 + g * 8;
            __builtin_amdgcn_global_load_lds(
                (const __attribute__((address_space(1))) u32*)ga,
                (__attribute__((address_space(3))) u32*)&As[(it * 256 + wave * 64) * 8],
                16, 0, 0);
            const u16* gb = B + (size_t)(n0 + row) * 1024 + k0 + g * 8;
            __builtin_amdgcn_global_load_lds(
                (const __attribute__((address_space(1))) u32*)gb,
                (__attribute__((address_space(3))) u32*)&Bs[(it * 256 + wave * 64) * 8],
                16, 0, 0);
        }
        __syncthreads();
        #pragma unroll
        for (int ks = 0; ks < 2; ks++) {
            const int gk = ks * 4 + (lane >> 4);
            const int rn = wn + (lane & 15);
            const int jb = gk ^ (rn & 7);
            const bf16x8 bfr = *(const bf16x8*)&Bs[rn * 64 + jb * 8];
            #pragma unroll
            for (int mi = 0; mi < 4; mi++) {
                const int rm = mi * 16 + (lane & 15);
                const int ja = gk ^ (rm & 7);
                const bf16x8 af = *(const bf16x8*)&As[rm * 64 + ja * 8];
                acc[mi] = __builtin_amdgcn_mfma_f32_16x16x32_bf16(af, bfr, acc[mi], 0, 0, 0);
            }
        }
    }
    const int col_l = lane & 15, row_l = (lane >> 4) * 4;
    #pragma unroll
    for (int mi = 0; mi < 4; mi++)
        #pragma unroll
        for (int i = 0; i < 4; i++)
            C[(size_t)(m0 + mi * 16 + row_l + i) * 1024 + n0 + wn + col_l] = f2bf(acc[mi][i]);
}

// ---------------------------------------------------------------------------
// 256x256-tile 8-phase bf16 MFMA GEMM (T2+T3+T4+T5 stack, m201 template).
// M=8192, N=1024, K=1024, z in {0..4} from the block decode. A (xb) shared
// across z; B/C z-strided.
//
// Geometry: 512 threads = 8 waves (2M x 4N); per-wave C = 128x64 = acc[8][4].
// LDS: [2 buf][A,B][2 half][128x64 bf16] = 128 KiB -> 1 block/CU, 2 waves/SIMD.
// Halves are quadrant-aligned; each LDS region's last read phase is unique:
//   A-h0: ph1   B-h0: ph1   B-h1: ph2   A-h1: ph3   (regs reused after).
// Stage issue (after the freeing phase's end barrier):
//   ph1: A-h1(t+1), B-h1(t+1)   ph2: A-h0(t+2)   ph4: B-h0(t+2)
// Counted waits: vmcnt(8) at ph1-end and ph4-end; never 0 in the main loop.
//
// ROUND-2 FIX: LDS reads are inline-asm ds_read_b128 (dsr128) + explicit
// lgkmcnt(0)+sched_barrier(0) before each MFMA cluster. C++ ds_reads from a
// dynamically-indexed buffer forced SIInsertWaitcnts' LDS-DMA alias tracking
// to emit s_waitcnt vmcnt(0) before every phase's first read (it cannot prove
// the read doesn't alias in-flight global_load_lds DMAs into the other
// buffer), draining the prefetch queue 64x/block -> the observed 109us/32%
// MfmaUtil in r1 AND r2. Opaque asm reads carry no mem operands, so the only
// VMEM ordering is our hand-placed counted vmcnt ledger (m201/m218 regime).
// REQUIRES grid == (640,1,1), 512 threads. 640%8==0 -> XCD decode bijective.
// ---------------------------------------------------------------------------
__global__ __launch_bounds__(512)
void mfma_gemm256(const u16* __restrict__ Asrc, const u16* __restrict__ Bt,
                  u16* __restrict__ Cout)
{
    __shared__ __align__(16) u16 Alds[2][2][8192];   // [buf][half(qm)][128*64]
    __shared__ __align__(16) u16 Blds[2][2][8192];   // [buf][half(qn)][128*64]

    const int flat  = blockIdx.x;
    const int xcd   = flat & 7;          // round-robin dispatch -> XCD id
    const int local = flat >> 3;         // 0..79, contiguous per XCD
    const int zb    = local >> 4;        // 0..4   (per-XCD: 16 blocks per z)
    const int rem   = local & 15;
    const int m0    = (xcd * 4 + (rem >> 2)) * 256;  // per-XCD A stripe: 2 MB
    const int n0    = (rem & 3) * 256;               // B slice: 2 MB

    const u16* A = Asrc;                               // shared across z
    const u16* B = Bt + (size_t)zb * 1048576;
    u16*       C = Cout + (size_t)zb * 8388608;

    const int tid  = threadIdx.x;
    const int lane = tid & 63, wave = tid >> 6;
    const int wmi  = wave >> 2, wni = wave & 3;        // 2 x 4 wave grid
    const int l15  = lane & 15, l4 = lane >> 4;

    f32x4 acc[8][4];
    #pragma unroll
    for (int i = 0; i < 8; i++)
        #pragma unroll
        for (int j = 0; j < 4; j++) acc[i][j] = (f32x4)0.f;

    bf16x8 a_fr[2][4];        // [ks][m-tile within quadrant]
    bf16x8 b_fr[2][2][2];     // [qn][ks][n-tile within quadrant]

// --- staging: linear LDS dest (wave-uniform base), swizzle on GLOBAL source.
#define STAGE_A(BUFP, HALF, T) do {                                           \
    _Pragma("unroll")                                                         \
    for (int it_ = 0; it_ < 2; it_++) {                                       \
        const int bc_ = it_ * 512 + wave * 64;                                \
        const int c_  = bc_ + lane;                                           \
        const int r_  = c_ >> 3, j_ = c_ & 7;                                 \
        const int g_  = j_ ^ (r_ & 7);                                        \
        const int gr_ = m0 + ((r_ >> 6) << 7) + (HALF) * 64 + (r_ & 63);      \
        const u16* ga_ = A + (size_t)gr_ * 1024 + (T) * 64 + g_ * 8;          \
        __builtin_amdgcn_global_load_lds(                                     \
            (const __attribute__((address_space(1))) u32*)ga_,                \
            (__attribute__((address_space(3))) u32*)&(BUFP)[(HALF)][bc_ * 8], \
            16, 0, 0);                                                        \
    } } while (0)

#define STAGE_B(BUFP, HALF, T) do {                                           \
    _Pragma("unroll")                                                         \
    for (int it_ = 0; it_ < 2; it_++) {                                       \
        const int bc_ = it_ * 512 + wave * 64;                                \
        const int c_  = bc_ + lane;                                           \
        const int r_  = c_ >> 3, j_ = c_ & 7;                                 \
        const int g_  = j_ ^ (r_ & 7);                                        \
        const int gr_ = n0 + ((r_ >> 5) << 6) + (HALF) * 32 + (r_ & 31);      \
        const u16* gb_ = B + (size_t)gr_ * 1024 + (T) * 64 + g_ * 8;          \
        __builtin_amdgcn_global_load_lds(                                     \
            (const __attribute__((address_space(1))) u32*)gb_,                \
            (__attribute__((address_space(3))) u32*)&(BUFP)[(HALF)][bc_ * 8], \
            16, 0, 0);                                                        \
    } } while (0)

#define READ_A(BUFP, QM) do {                                                 \
    _Pragma("unroll") for (int ks_ = 0; ks_ < 2; ks_++)                       \
    _Pragma("unroll") for (int m4_ = 0; m4_ < 4; m4_++) {                     \
        const int r_  = wmi * 64 + m4_ * 16 + l15;                            \
        const int gk_ = ks_ * 4 + l4;                                         \
        a_fr[ks_][m4_] =                                                      \
            dsr128(&(BUFP)[QM][r_ * 64 + ((gk_ ^ (r_ & 7)) * 8)]);            \
    } } while (0)

#define READ_B(BUFP, QN) do {                                                 \
    _Pragma("unroll") for (int ks_ = 0; ks_ < 2; ks_++)                       \
    _Pragma("unroll") for (int n2_ = 0; n2_ < 2; n2_++) {                     \
        const int r_  = wni * 32 + n2_ * 16 + l15;                            \
        const int gk_ = ks_ * 4 + l4;                                         \
        b_fr[QN][ks_][n2_] =                                                  \
            dsr128(&(BUFP)[QN][r_ * 64 + ((gk_ ^ (r_ & 7)) * 8)]);            \
    } } while (0)

#define MFMA_PH(QM, QN) do {                                                  \
    __builtin_amdgcn_s_setprio(1);                                            \
    _Pragma("unroll") for (int ks_ = 0; ks_ < 2; ks_++)                       \
    _Pragma("unroll") for (int m4_ = 0; m4_ < 4; m4_++)                       \
    _Pragma("unroll") for (int n2_ = 0; n2_ < 2; n2_++)                       \
        acc[(QM) * 4 + m4_][(QN) * 2 + n2_] =                                 \
            __builtin_amdgcn_mfma_f32_16x16x32_bf16(                          \
                a_fr[ks_][m4_], b_fr[QN][ks_][n2_],                           \
                acc[(QM) * 4 + m4_][(QN) * 2 + n2_], 0, 0, 0);                \
    __builtin_amdgcn_s_setprio(0);                                            \
} while (0)

// Sync: builtin barrier (no fence), clobber-free counted waits pinned with
// sched_barrier(0). LGKM0 before each MFMA cluster consuming fresh asm reads
// (rule #18: MFMA is register-only, "memory" doesn't order it; the fence is
// sched_barrier(0) right after the waitcnt).
#define BAR()    __builtin_amdgcn_s_barrier()
#define LGKM0()  do { __asm__ volatile("s_waitcnt lgkmcnt(0)");               \
                      __builtin_amdgcn_sched_barrier(0); } while (0)
#define VMCNT8() do { __asm__ volatile("s_waitcnt vmcnt(8)");                 \
                      __builtin_amdgcn_sched_barrier(0); } while (0)
#define VMCNT4() do { __asm__ volatile("s_waitcnt vmcnt(4)");                 \
                      __builtin_amdgcn_sched_barrier(0); } while (0)
#define VMCNT0() do { __asm__ volatile("s_waitcnt vmcnt(0)");                 \
                      __builtin_amdgcn_sched_barrier(0); } while (0)

    // prologue: issue order fixes the per-wave vmcnt ledger:
    //   [A0h0 B0h0 A0h1 B0h1 A1h0 B1h0] = 12 loads; vmcnt(8) completes A0h0,B0h0.
    STAGE_A(Alds[0], 0, 0);
    STAGE_B(Blds[0], 0, 0);
    STAGE_A(Alds[0], 1, 0);
    STAGE_B(Blds[0], 1, 0);
    STAGE_A(Alds[1], 0, 1);
    STAGE_B(Blds[1], 0, 1);
    VMCNT8(); BAR();

    #pragma unroll 1
    for (int t = 0; t < 16; ++t) {
        const int b = t & 1, nb = b ^ 1;
        u16 (*Ab)[8192] = Alds[b];
        u16 (*Bb)[8192] = Blds[b];

        // ---- phase 1: quadrant (0,0) ----
        READ_A(Ab, 0);
        READ_B(Bb, 0);
        if (t + 1 < 16) { STAGE_A(Alds[nb], 1, t + 1); STAGE_B(Blds[nb], 1, t + 1); }
        BAR();
        LGKM0();
        MFMA_PH(0, 0);
        if (t < 15) { VMCNT8(); } else { VMCNT0(); }   // completes A-h1(t),B-h1(t)
        BAR();

        // ---- phase 2: quadrant (0,1) ----  (a_fr reused)
        READ_B(Bb, 1);
        if (t + 2 < 16) STAGE_A(Alds[b], 0, t + 2);    // A-h0(b) freed at ph1-end
        BAR();
        LGKM0();
        MFMA_PH(0, 1);
        BAR();

        // ---- phase 3: quadrant (1,0) ----  (b_fr[0] reused)
        READ_A(Ab, 1);
        BAR();
        LGKM0();
        MFMA_PH(1, 0);
        BAR();

        // ---- phase 4: quadrant (1,1) ----  (a_fr + b_fr[1] reused, no new reads)
        if (t + 2 < 16) STAGE_B(Blds[b], 0, t + 2);    // B-h0(b) freed at ph1-end
        BAR();
        MFMA_PH(1, 1);
        if (t + 2 < 16)      { VMCNT8(); }             // completes A-h0(t+1),B-h0(t+1)
        else if (t + 1 < 16) { VMCNT4(); }             // t==14 tail
        BAR();
    }

#undef STAGE_A
#undef STAGE_B
#undef READ_A
#undef READ_B
#undef MFMA_PH
#undef BAR
#undef LGKM0
#undef VMCNT8
#undef VMCNT4
#undef VMCNT0

    // epilogue: C/D layout col=lane&15, row=(lane>>4)*4+reg  [m89-verified]
    const int col_l = lane & 15, row_l = (lane >> 4) * 4;
    #pragma unroll
    for (int mi = 0; mi < 8; mi++)
        #pragma unroll
        for (int ni = 0; ni < 4; ni++)
            #pragma unroll
            for (int i = 0; i < 4; i++) {
                const int rw = m0 + wmi * 128 + mi * 16 + row_l + i;
                const int cn = n0 + wni * 64 + ni * 16 + col_l;
                C[(size_t)rw * 1024 + cn] = f2bf(acc[mi][ni][i]);
            }
}

// ---------------------------------------------------------------------------
// 128x128-tile bf16 MFMA GEMM, M=8192, N=K=1024, z-batched. XCD-swizzled
// block decode (flat%8 = XCD under round-robin) pins an 8-row m-group per
// XCD: per-z working set A 2MB + B 2MB fits the 4MB XCD L2.
// REQUIRES grid == (8, 64, Z).  (Kept for the final fp32-out projection.)
// ---------------------------------------------------------------------------
template<int OUTBF>
__global__ __launch_bounds__(256)
void mfma_gemm(const u16* __restrict__ Asrc, const u16* __restrict__ Bt,
               void* __restrict__ Cout, size_t astride, size_t bstride, size_t cstride)
{
    __shared__ u16 As[128 * 64];
    __shared__ u16 Bs[128 * 64];
    const int flat = blockIdx.x + 8 * (blockIdx.y + 64 * blockIdx.z);
    const int xcd = flat & 7;
    const int r   = flat >> 3;
    const int nb = r & 7, mlocal = (r >> 3) & 7, zb = r >> 6;
    const int m0 = (xcd * 8 + mlocal) * 128, n0 = nb * 128;

    const u16* A = Asrc + (size_t)zb * astride;
    const u16* B = Bt   + (size_t)zb * bstride;
    const int tid  = threadIdx.x;
    const int lane = tid & 63, wave = tid >> 6;
    const int wm = (wave >> 1) * 64, wn = (wave & 1) * 64;

    f32x4 acc[4][4];
    #pragma unroll
    for (int i = 0; i < 4; i++)
        #pragma unroll
        for (int j = 0; j < 4; j++) acc[i][j] = (f32x4)0.f;

    for (int k0 = 0; k0 < 1024; k0 += 64) {
        __syncthreads();
        #pragma unroll
        for (int it = 0; it < 4; it++) {
            const int c   = it * 256 + tid;
            const int row = c >> 3, j = c & 7;
            const int g   = j ^ (row & 7);
            const u16* ga = A + (size_t)(m0 + row) * 1024 + k0 + g * 8;
            __builtin_amdgcn_global_load_lds(
                (const __attribute__((address_space(1))) u32*)ga,
                (__attribute__((address_space(3))) u32*)&As[(it * 256 + wave * 64) * 8],
                16, 0, 0);
            const u16* gb = B + (size_t)(n0 + row) * 1024 + k0 + g * 8;
            __builtin_amdgcn_global_load_lds(
                (const __attribute__((address_space(1))) u32*)gb,
                (__attribute__((address_space(3))) u32*)&Bs[(it * 256 + wave * 64) * 8],
                16, 0, 0);
        }
        __syncthreads();
        #pragma unroll
        for (int ks = 0; ks < 2; ks++) {
            bf16x8 af[4], bfr[4];
            const int gk = ks * 4 + (lane >> 4);
            #pragma unroll
            for (int mi = 0; mi < 4; mi++) {
                const int rr  = wm + mi * 16 + (lane & 15);
                const int ja = gk ^ (rr & 7);
                af[mi] = *(const bf16x8*)&As[rr * 64 + ja * 8];
                const int rn = wn + mi * 16 + (lane & 15);
                const int jb = gk ^ (rn & 7);
                bfr[mi] = *(const bf16x8*)&Bs[rn * 64 + jb * 8];
            }
            #pragma unroll
            for (int mi = 0; mi < 4; mi++)
                #pragma unroll
                for (int ni = 0; ni < 4; ni++)
                    acc[mi][ni] = __builtin_amdgcn_mfma_f32_16x16x32_bf16(
                        af[mi], bfr[ni], acc[mi][ni], 0, 0, 0);
        }
    }
    // epilogue: C/D layout col=lane&15, row=(lane>>4)*4+reg  [m89-verified]
    const int col_l = lane & 15, row_l = (lane >> 4) * 4;
    if (OUTBF) {
        u16* C = (u16*)Cout + (size_t)zb * cstride;
        #pragma unroll
        for (int mi = 0; mi < 4; mi++)
            #pragma unroll
            for (int ni = 0; ni < 4; ni++)
                #pragma unroll
                for (int i = 0; i < 4; i++) {
                    const int rw  = m0 + wm + mi * 16 + row_l + i;
                    const int cn = n0 + wn + ni * 16 + col_l;
                    C[(size_t)rw * 1024 + cn] = f2bf(acc[mi][ni][i]);
                }
    } else {
        float* C = (float*)Cout + (size_t)zb * cstride;
        #pragma unroll
        for (int mi = 0; mi < 4; mi++)
            #pragma unroll
            for (int ni = 0; ni < 4; ni++)
                #pragma unroll
                for (int i = 0; i < 4; i++) {
                    const int rw  = m0 + wm + mi * 16 + row_l + i;
                    const int cn = n0 + wn + ni * 16 + col_l;
                    C[(size_t)rw * 1024 + cn] = acc[mi][ni][i];
                }
    }
}

// ---------------------------------------------------------------------------
// Chunk-parallel scan, CT=32, NC=64. s_t = a_t*s_{t-1} + sigmoid(g)*k*v.
// 256-thread blocks = 4 independent wave-units (no intra-block sync needed).
// scan1: local scan per chunk; writes rounded kv product (kvb), chunk-local
// state Lc[ci][d] and decay product Pc[ci].
// ---------------------------------------------------------------------------
__global__ __launch_bounds__(256)
void scan1(const u16* __restrict__ Kq, const u16* __restrict__ Vq, const u16* __restrict__ Gq,
           const float* __restrict__ dec, u16* __restrict__ kvb,
           float* __restrict__ Lc, float* __restrict__ Pc)
{
    const int unit = blockIdx.x * 4 + (threadIdx.x >> 6);   // 0..4095
    const int d = threadIdx.x & 63;
    const int c = unit & (NC - 1), h = (unit >> 6) & 15, b = unit >> 10;
    const size_t t0 = (size_t)b * SEQ + c * CT;
    const size_t base = t0 * 1024 + h * 64 + d;
    const u16* kp = Kq + base;
    const u16* vp = Vq + base;
    const u16* gp = Gq + base;
    const float* dp = dec + t0 * 16 + h;
    float s = 0.f, P = 1.f;
    #pragma unroll 4
    for (int t = 0; t < CT; t++) {
        const size_t o = (size_t)t * 1024;
        const float a  = dp[t * 16];
        const u16 kq = f2bf(b2f(kp[o]) * b2f(vp[o]) * sigf(b2f(gp[o])));
        kvb[base + o] = kq;
        s = fmaf(a, s, b2f(kq));
        P *= a;
    }
    const int ci = (b * 16 + h) * NC + c;
    Lc[(size_t)ci * 64 + d] = s;
    if (d == 0) Pc[ci] = P;
}

// scan2 folded into scan3: each unit combines its chunk prefix inline.
__global__ __launch_bounds__(256)
void scan3(const u16* __restrict__ Qq, const u16* __restrict__ kvb,
           const float* __restrict__ dec,
           const float* __restrict__ Lc, const float* __restrict__ Pc,
           u16* __restrict__ attb)
{
    const int unit = blockIdx.x * 4 + (threadIdx.x >> 6);
    const int d = threadIdx.x & 63;
    const int c = unit & (NC - 1), h = (unit >> 6) & 15, b = unit >> 10;
    const size_t t0 = (size_t)b * SEQ + c * CT;
    const size_t base = t0 * 1024 + h * 64 + d;
    const u16* qp = Qq + base;
    const u16* kp = kvb + base;
    const float* dp = dec + t0 * 16 + h;

    // inline prefix combine over earlier chunks of this (b,h)
    const int ci0 = (b * 16 + h) * NC;
    float s = 0.f;
    for (int cc = 0; cc < c; cc++)
        s = fmaf(Pc[ci0 + cc], s, Lc[(size_t)(ci0 + cc) * 64 + d]);

    #pragma unroll 4
    for (int t = 0; t < CT; t++) {
        const size_t o = (size_t)t * 1024;
        const float a  = dp[t * 16];
        s = fmaf(a, s, b2f(kp[o]));
        attb[base + o] = f2bf(b2f(qp[o]) * s);
    }
}

// ---------------------------------------------------------------------------
// RMSNorm * rms_w * sigmoid(gpre) -> bf16. One wave per token (4 tokens per
// block), butterfly-only reduction, no LDS/syncthreads.
// ---------------------------------------------------------------------------
__global__ __launch_bounds__(256)
void rms_gate(const u16* __restrict__ attb, const u16* __restrict__ gpre,
              const float* __restrict__ rmsw, u16* __restrict__ o)
{
    const int wave = threadIdx.x >> 6, lane = threadIdx.x & 63;
    const size_t t = (size_t)blockIdx.x * 4 + wave;
    const ushort4* ap = (const ushort4*)(attb + t * 1024);
    ushort4 a4[4];
    float ss = 0.f;
    #pragma unroll
    for (int i = 0; i < 4; i++) {
        a4[i] = ap[lane + 64 * i];
        const float ax = b2f(a4[i].x), ay = b2f(a4[i].y);
        const float az = b2f(a4[i].z), aw = b2f(a4[i].w);
        ss += ax*ax + ay*ay + az*az + aw*aw;
    }
    #pragma unroll
    for (int off = 32; off > 0; off >>= 1) ss += __shfl_xor(ss, off);
    const float scale = rsqrtf(ss * (1.0f / 1024.0f) + 1.1920929e-7f);
    const ushort4* gp = (const ushort4*)(gpre + t * 1024);
    const float4*  wp = (const float4*)rmsw;
    uint2* op = (uint2*)(o + t * 1024);
    #pragma unroll
    for (int i = 0; i < 4; i++) {
        const ushort4 g4 = gp[lane + 64 * i];
        const float4  w  = wp[lane + 64 * i];
        __align__(8) u16 r[4];
        r[0] = f2bf(b2f(a4[i].x) * scale * w.x * sigf(b2f(g4.x)));
        r[1] = f2bf(b2f(a4[i].y) * scale * w.y * sigf(b2f(g4.y)));
        r[2] = f2bf(b2f(a4[i].z) * scale * w.z * sigf(b2f(g4.z)));
        r[3] = f2bf(b2f(a4[i].w) * scale * w.w * sigf(b2f(g4.w)));
        op[lane + 64 * i] = *(const uint2*)r;
    }
}

// ---------------------------------------------------------------------------
extern "C" void kernel_launch(void* const* d_in, const int* in_sizes, int n_in,
                              void* d_out, int out_size, void* d_ws, size_t ws_size,
                              hipStream_t stream)
{
    const float* x    = (const float*)d_in[0];
    const float* qU   = (const float*)d_in[1];
    const float* qV   = (const float*)d_in[2];
    const float* kU   = (const float*)d_in[3];
    const float* kV   = (const float*)d_in[4];
    const float* vU   = (const float*)d_in[5];
    const float* vV   = (const float*)d_in[6];
    const float* ql   = (const float*)d_in[7];
    const float* kl   = (const float*)d_in[8];
    const float* vl   = (const float*)d_in[9];
    const float* gl   = (const float*)d_in[10];
    const float* dw   = (const float*)d_in[11];
    const float* db   = (const float*)d_in[12];
    const float* ogw  = (const float*)d_in[13];
    const float* opw  = (const float*)d_in[14];
    const float* rmsw = (const float*)d_in[15];

    // workspace layout (byte offsets, ~165.2 MB total)
    char* w = (char*)d_ws;
    float* dec  = (float*)(w + 0);           // 512 KB
    u16*   WT   = (u16*)  (w + 524288);      // 5 slices x 2 MB (slice4 = ogwb)
    u16*   xb   = (u16*)  (w + 11010048);    // 16 MB
    u16*   opwb = (u16*)  (w + 27787264);    // 2 MB
    u16*   QKVG = (u16*)  (w + 29884416);    // 5 slices x 16 MB (q,k,v,g,gpre)
    u16*   RMSO = (u16*)  (w + 113770496);   // 16 MB
    u16*   ATTb = (u16*)  (w + 130547712);   // 16 MB
    u16*   kvb  = (u16*)  (w + 147324928);   // 16 MB
    float* Lc   = (float*)(w + 164102144);   // 1 MB
    float* Pc   = (float*)(w + 165150720);   // 16 KB
    // gU/gVT alias the QKVG region (consumed by weff-gemm before QKVG written)
    u16*   gU   = QKVG;                      // 8 MB
    u16*   gVT  = QKVG + 4194304;            // 8 MB
    u16*   ogwb = WT + 4 * 1048576;          // WT slice 4
    u16*   GPRE = QKVG + 4 * 8388608;        // QKVG slice 4

    // 1. prep: x cast + decay fused (x row in regs), weight casts, gathers
    prep<<<6144, 256, 0, stream>>>(x, ogw, opw, qU, kU, vU, qV, kV, vV,
                                   ql, kl, vl, gl, dw, db,
                                   xb, ogwb, opwb, gU, gVT, dec);

    // 2. WT[p][o][d] = sum_k gVT[p][o,k] * gU[p][d,k]  (= W_eff^T)
    mfma_gemm64<<<dim3(16, 16, 4), 256, 0, stream>>>(gVT, gU, WT);

    // 3. q,k,v,gate,gpre = x @ {W_eff_p, out_gate_w}^T -> bf16, z=5 batch
    //    256^2-tile 8-phase counted-vmcnt kernel (T2+T3+T4+T5).
    mfma_gemm256<<<640, 512, 0, stream>>>(xb, WT, QKVG);

    // 4-5. chunk-parallel scan (prefix combine inlined in scan3)
    scan1<<<1024, 256, 0, stream>>>(QKVG + 8388608, QKVG + 16777216, QKVG + 25165824,
                                    dec, kvb, Lc, Pc);
    scan3<<<1024, 256, 0, stream>>>(QKVG, kvb, dec, Lc, Pc, ATTb);

    // 6. rmsnorm * gate
    rms_gate<<<2048, 256, 0, stream>>>(ATTb, GPRE, rmsw, RMSO);

    // 7. final: rmso @ out_proj_w^T -> fp32 d_out
    mfma_gemm<0><<<dim3(8, 64, 1), 256, 0, stream>>>(RMSO, opwb, (float*)d_out, 0, 0, 0);
}